// Round 3
// baseline (655.469 us; speedup 1.0000x reference)
//
#include <hip/hip_runtime.h>
#include <hip/hip_bf16.h>

// Problem constants: B=8, L=512, N=64, D=1024
constexpr int Lseq = 512;
constexpr int Nsp  = 64;
constexpr int Dm   = 1024;   // D
constexpr int D2   = 2048;   // 2D

typedef __attribute__((ext_vector_type(8))) short short8;
typedef __attribute__((ext_vector_type(4))) float floatx4;
typedef unsigned short u16;
typedef unsigned int   u32;

__device__ __forceinline__ u32 f2bf(float x) {
    u32 u = __float_as_uint(x);
    return (u + 0x7fffu + ((u >> 16) & 1u)) >> 16;   // RNE
}
__device__ __forceinline__ float bf2f(u32 hbits) {
    return __uint_as_float(hbits << 16);
}
__device__ __forceinline__ u32 pk2(float x0, float x1) {
    __hip_bfloat162 bb = __float22bfloat162_rn(make_float2(x0, x1));
    u32 r; __builtin_memcpy(&r, &bb, 4); return r;
}

// ---------------------------------------------------------------------------
// Swizzle for [R][64]-u16 (128 B-row) LDS tiles: physical chunk =
// logical chunk ^ (row&7).  u16 index: row*64 + ((chunk ^ (row&7))*8) + off.
// Fragment reads (rows x*16+lr, 16 rows per lq-phase) then alias only 2-way
// (free).  global_load_lds writes linearly, so the GLOBAL source chunk is
// pre-swizzled: lane l of gload i covers physical row i*8+(l>>3), phys chunk
// l&7  ->  logical chunk (l&7)^((l>>3)&7)  (row&7 == l>>3 when base%8==0).
// ---------------------------------------------------------------------------

// ---------------------------------------------------------------------------
// Gather h rows at span indices, emitting hi/lo bf16 split. grid (512,2).
// ---------------------------------------------------------------------------
__global__ __launch_bounds__(256)
void gather_split(const float* __restrict__ h, const int* __restrict__ span,
                  u16* __restrict__ g_hi, u16* __restrict__ g_lo)
{
    const int row = blockIdx.x, which = blockIdx.y;
    const int b = row >> 6;
    const int idx = span[row * 2 + which];
    const float4* src = (const float4*)(h + ((size_t)b * Lseq + idx) * Dm);
    float4 v = src[threadIdx.x];
    u32 h01 = pk2(v.x, v.y), h23 = pk2(v.z, v.w);
    u32 l01 = pk2(v.x - bf2f(h01 & 0xffffu), v.y - bf2f(h01 >> 16));
    u32 l23 = pk2(v.z - bf2f(h23 & 0xffffu), v.w - bf2f(h23 >> 16));
    size_t off = ((size_t)which * 512 + row) * Dm + (size_t)threadIdx.x * 4;
    *(uint2*)(g_hi + off) = make_uint2(h01, h23);
    *(uint2*)(g_lo + off) = make_uint2(l01, l23);
}

// Plain fp32 gather (fallback path)
__global__ __launch_bounds__(256)
void gather_rows(const float* __restrict__ h, const int* __restrict__ span,
                 float* __restrict__ gs, float* __restrict__ ge)
{
    const int row = blockIdx.x, which = blockIdx.y;
    const int b = row >> 6;
    const int idx = span[row * 2 + which];
    const float4* src = (const float4*)(h + ((size_t)b * Lseq + idx) * Dm);
    float4* dst = (float4*)((which ? ge : gs) + (size_t)row * Dm);
    dst[threadIdx.x] = src[threadIdx.x];
}

// ---------------------------------------------------------------------------
// Batched weight transpose+split: W[k][n] fp32 -> Wt_hi/lo[n][k] bf16.
// ---------------------------------------------------------------------------
struct TransJobs {
    const float* src[8];
    u16* dh[8];
    u16* dl[8];
    int K[8], N[8], tiles[8];
};

__global__ __launch_bounds__(256)
void transpose_split(TransJobs J)
{
    __shared__ float T[64][65];
    int b = blockIdx.x, j = 0;
    while (b >= J.tiles[j]) { b -= J.tiles[j]; ++j; }
    const float* src = J.src[j];
    const int K = J.K[j], N = J.N[j];
    const int tk = K >> 6;
    const int k0 = (b % tk) * 64, n0 = (b / tk) * 64;
    const int t = threadIdx.x, c = t & 63, r4 = t >> 6;
#pragma unroll
    for (int s = 0; s < 16; ++s) {
        int r = r4 * 16 + s;
        T[r][c] = src[(size_t)(k0 + r) * N + n0 + c];
    }
    __syncthreads();
    u16* dh = J.dh[j];
    u16* dl = J.dl[j];
#pragma unroll
    for (int s = 0; s < 16; ++s) {
        int n = r4 * 16 + s;
        float v = T[c][n];
        u32 hv = f2bf(v);
        dh[(size_t)(n0 + n) * K + k0 + c] = (u16)hv;
        if (dl) dl[(size_t)(n0 + n) * K + k0 + c] = (u16)f2bf(v - bf2f(hv));
    }
}

// ---------------------------------------------------------------------------
// Split-bf16 MFMA GEMM: C = act(A @ W + bias), A as hi/lo bf16 [M][K],
// W pre-transposed+split Wt_hi/lo[n][k]. Tile 64x64, K-step 64 (v4: halves
// the barrier-drain count; mid-GEMMs are drain-latency-bound at 1-2
// blocks/CU). 4 waves; wave w owns rows [w*16, w*16+16). 3 MFMAs per tile
// pair. LDS 128B-row tiles with chunk^row&7 swizzle both sides.
// ---------------------------------------------------------------------------
struct GemmP {
    const u16 *ah0, *ah1, *al0, *al1;
    const u16 *wh0, *wh1, *wl0, *wl1;
    const float *b0, *b1;
    float *of0, *of1;
    u16 *oh0, *oh1, *ol0, *ol1;
    int K, ldc, coloff1;
};

template<bool RELU, bool BIAS, bool SPLIT_OUT>
__global__ __launch_bounds__(256)
void gemm_split(GemmP P)
{
    __shared__ __align__(16) u16 As_h[64 * 64];
    __shared__ __align__(16) u16 As_l[64 * 64];
    __shared__ __align__(16) u16 Bs_h[64 * 64];
    __shared__ __align__(16) u16 Bs_l[64 * 64];

    const int tid = threadIdx.x, w = tid >> 6, l = tid & 63;
    const int lr = l & 15, lq = l >> 4;
    const int z = blockIdx.z;
    const int m0 = blockIdx.x * 64, n0 = blockIdx.y * 64;
    const int K = P.K;

    const u16* ah = z ? P.ah1 : P.ah0;
    const u16* al = z ? P.al1 : P.al0;
    const u16* wh = z ? P.wh1 : P.wh0;
    const u16* wl = z ? P.wl1 : P.wl0;

    // Each wave stages one 64x64 bf16 tile (8 KB) via 8 global_load_lds.
    const u16* src; u16* ldst;
    if      (w == 0) { src = ah + (size_t)m0 * K; ldst = As_h; }
    else if (w == 1) { src = al + (size_t)m0 * K; ldst = As_l; }
    else if (w == 2) { src = wh + (size_t)n0 * K; ldst = Bs_h; }
    else             { src = wl + (size_t)n0 * K; ldst = Bs_l; }
    // pre-swizzled source chunk (see swizzle comment above)
    const int schunk = (l & 7) ^ ((l >> 3) & 7);
    const u16* sl = src + (size_t)(l >> 3) * K + (size_t)schunk * 8;

    // fragment-read swizzle: row&7 == lr&7 for rows x*16+lr
    const int rswz = (lr & 7) << 3;

    floatx4 acc[4];
#pragma unroll
    for (int nt = 0; nt < 4; ++nt) acc[nt] = (floatx4){0.f, 0.f, 0.f, 0.f};

    for (int k0 = 0; k0 < K; k0 += 64) {
        __syncthreads();
#pragma unroll
        for (int i = 0; i < 8; ++i)
            __builtin_amdgcn_global_load_lds(
                (const __attribute__((address_space(1))) u32*)(sl + (size_t)i * 8 * K + k0),
                (__attribute__((address_space(3))) u32*)(ldst + i * 512), 16, 0, 0);
        __syncthreads();

#pragma unroll
        for (int kk = 0; kk < 2; ++kk) {
            const int ar = (((w * 16 + lr) * 64) + kk * 32 + lq * 8) ^ rswz;
            short8 fah = *(const short8*)&As_h[ar];
            short8 fal = *(const short8*)&As_l[ar];
#pragma unroll
            for (int nt = 0; nt < 4; ++nt) {
                const int brd = (((nt * 16 + lr) * 64) + kk * 32 + lq * 8) ^ rswz;
                short8 fbh = *(const short8*)&Bs_h[brd];
                short8 fbl = *(const short8*)&Bs_l[brd];
                acc[nt] = __builtin_amdgcn_mfma_f32_16x16x32_bf16(fah, fbh, acc[nt], 0, 0, 0);
                acc[nt] = __builtin_amdgcn_mfma_f32_16x16x32_bf16(fal, fbh, acc[nt], 0, 0, 0);
                acc[nt] = __builtin_amdgcn_mfma_f32_16x16x32_bf16(fah, fbl, acc[nt], 0, 0, 0);
            }
        }
    }

    const float* bias = z ? P.b1 : P.b0;
    const int colb = n0 + (z ? P.coloff1 : 0);
    float bv[4];
    if (BIAS) {
#pragma unroll
        for (int nt = 0; nt < 4; ++nt) bv[nt] = bias[n0 + nt * 16 + lr];
    }
#pragma unroll
    for (int nt = 0; nt < 4; ++nt) {
#pragma unroll
        for (int r = 0; r < 4; ++r) {
            float x = acc[nt][r];
            if (BIAS) x += bv[nt];
            if (RELU) x = fmaxf(x, 0.f);
            const int m = m0 + w * 16 + lq * 4 + r;
            const size_t oidx = (size_t)m * P.ldc + colb + nt * 16 + lr;
            if (SPLIT_OUT) {
                u16* oh = z ? P.oh1 : P.oh0;
                u16* ol = z ? P.ol1 : P.ol0;
                u32 hv = f2bf(x);
                oh[oidx] = (u16)hv;
                ol[oidx] = (u16)f2bf(x - bf2f(hv));
            } else {
                float* of = z ? P.of1 : P.of0;
                of[oidx] = x;
            }
        }
    }
}

// ---------------------------------------------------------------------------
// fp32 GEMM fallback (round-1) for small layers if ws is too small.
// ---------------------------------------------------------------------------
template<bool RELU, bool BIAS>
__global__ __launch_bounds__(256)
void gemm_f32(const float* __restrict__ A, int lda,
              const float* __restrict__ W, int ldw,
              const float* __restrict__ bias,
              float* __restrict__ C, int ldc, int K)
{
    __shared__ float As[16][64];
    __shared__ float Ws[16][64];
    const int tid = threadIdx.x;
    const int tx = tid & 15, ty = tid >> 4;
    const int m0 = blockIdx.x * 64, n0 = blockIdx.y * 64;
    const int la_c = tid & 15, la_r = tid >> 4;
    const int lw_n = tid & 63, lw_k = tid >> 6;
    float acc[4][4] = {};
    for (int k0 = 0; k0 < K; k0 += 16) {
#pragma unroll
        for (int s = 0; s < 4; ++s) {
            int m = la_r + 16 * s;
            As[la_c][m] = A[(size_t)(m0 + m) * lda + k0 + la_c];
        }
#pragma unroll
        for (int s = 0; s < 4; ++s) {
            int k = lw_k + 4 * s;
            Ws[k][lw_n] = W[(size_t)(k0 + k) * ldw + n0 + lw_n];
        }
        __syncthreads();
#pragma unroll
        for (int kk = 0; kk < 16; ++kk) {
            float a4[4], w4[4];
            *(float4*)a4 = *(const float4*)&As[kk][ty * 4];
            *(float4*)w4 = *(const float4*)&Ws[kk][tx * 4];
#pragma unroll
            for (int i = 0; i < 4; ++i)
#pragma unroll
                for (int j = 0; j < 4; ++j)
                    acc[i][j] = fmaf(a4[i], w4[j], acc[i][j]);
        }
        __syncthreads();
    }
#pragma unroll
    for (int i = 0; i < 4; ++i) {
        float4 v; float* vp = (float*)&v;
#pragma unroll
        for (int j = 0; j < 4; ++j) {
            float x = acc[i][j];
            if (BIAS) x += bias[n0 + tx * 4 + j];
            if (RELU) x = fmaxf(x, 0.f);
            vp[j] = x;
        }
        *(float4*)&C[(size_t)(m0 + ty * 4 + i) * ldc + n0 + tx * 4] = v;
    }
}

// ---------------------------------------------------------------------------
// Final GEMM via bf16 MFMA; hidden = relu(hi ⊕ hj + br1) built on the fly.
// 512 threads, 8 waves (wm 0..1 × wn 0..3), tile 128(M)x256(N), grid (256,4).
// v4: K-step 64 (half the barrier drains). 128B-row swizzled tiles
// (chunk^row&7) on both sides.  B gload_lds issued before A-build VALU.
// ---------------------------------------------------------------------------
__global__ __launch_bounds__(512, 4)
void big_mfma(const float* __restrict__ hi, const float* __restrict__ hj,
              const float* __restrict__ br1, const u16* __restrict__ Wt,
              const float* __restrict__ br2, float* __restrict__ out)
{
    __shared__ float hiP[2][D2];                     // 16 KB
    __shared__ __align__(16) u16 Asb[128 * 64];      // swizzled [128][64], 16 KB
    __shared__ __align__(16) u16 Bsb[256 * 64];      // swizzled [256][64], 32 KB

    const int tid = threadIdx.x;
    const int p = blockIdx.x, n0 = blockIdx.y * 256;
    const int b = p >> 5, bi0 = p * 2;

    // A-build assignment: one row, chunks kq and kq+4, per thread.
    const int rowA = tid >> 2, kq = tid & 3;
    const int selA = rowA >> 6, jA = rowA & 63;
    const float* hjbase = hj + ((size_t)b * 64 + jA) * D2;
    const int o1 = kq * 8, o2 = o1 + 32;
    const int sA = rowA & 7;
    u16* ast1 = Asb + rowA * 64 + ((kq ^ sA) * 8);
    u16* ast2 = Asb + rowA * 64 + (((kq + 4) ^ sA) * 8);
    const float* hp = hiP[selA];

    // Prefetch hj chunks for k0=0 (in flight during hiP staging).
    float4 pa0 = *(const float4*)(hjbase + o1);
    float4 pa1 = *(const float4*)(hjbase + o1 + 4);
    float4 pb0 = *(const float4*)(hjbase + o2);
    float4 pb1 = *(const float4*)(hjbase + o2 + 4);

    // hiP = hi(+pair) + br1  (1024 float4 over 512 threads)
    {
        const float4* h0 = (const float4*)(hi + (size_t)bi0 * D2);
        const float4* h1 = (const float4*)(hi + (size_t)(bi0 + 1) * D2);
        const float4* br = (const float4*)br1;
        float4* d0 = (float4*)hiP[0];
        float4* d1 = (float4*)hiP[1];
        const int v = tid;   // 512 threads, 512 float4 per row
        float4 bb = br[v];
        float4 a = h0[v];
        a.x += bb.x; a.y += bb.y; a.z += bb.z; a.w += bb.w;
        d0[v] = a;
        float4 c = h1[v];
        c.x += bb.x; c.y += bb.y; c.z += bb.z; c.w += bb.w;
        d1[v] = c;
    }

    const int w = tid >> 6, l = tid & 63;
    const int wm = w & 1, wn = w >> 1;
    const int lr = l & 15, lq = l >> 4;
    const int rswz = (lr & 7) << 3;

    // B source: pre-swizzled chunk so linear gload write == swizzled layout.
    const int schunk = (l & 7) ^ ((l >> 3) & 7);

    floatx4 acc[4][4];
#pragma unroll
    for (int mt = 0; mt < 4; ++mt)
#pragma unroll
        for (int nt = 0; nt < 4; ++nt)
            acc[mt][nt] = (floatx4){0.f, 0.f, 0.f, 0.f};

    for (int k0 = 0; k0 < D2; k0 += 64) {
        __syncthreads();

        // ---- B tile: async bf16 stage first (hides under A-build) ----
#pragma unroll
        for (int i = 0; i < 4; ++i) {
            const u16* g = Wt + (size_t)(n0 + w * 32 + i * 8 + (l >> 3)) * D2
                              + k0 + schunk * 8;
            u16* lp = Bsb + w * 2048 + i * 512;
            __builtin_amdgcn_global_load_lds(
                (const __attribute__((address_space(1))) u32*)g,
                (__attribute__((address_space(3))) u32*)lp, 16, 0, 0);
        }

        // ---- A tile: relu(hi' + hj) -> bf16, swizzled stores ----
        {
            float4 h0 = *(const float4*)(hp + k0 + o1);
            float4 h1 = *(const float4*)(hp + k0 + o1 + 4);
            u32 u0 = pk2(fmaxf(pa0.x + h0.x, 0.f), fmaxf(pa0.y + h0.y, 0.f));
            u32 u1 = pk2(fmaxf(pa0.z + h0.z, 0.f), fmaxf(pa0.w + h0.w, 0.f));
            u32 u2 = pk2(fmaxf(pa1.x + h1.x, 0.f), fmaxf(pa1.y + h1.y, 0.f));
            u32 u3 = pk2(fmaxf(pa1.z + h1.z, 0.f), fmaxf(pa1.w + h1.w, 0.f));
            *(uint4*)ast1 = make_uint4(u0, u1, u2, u3);

            float4 g0 = *(const float4*)(hp + k0 + o2);
            float4 g1 = *(const float4*)(hp + k0 + o2 + 4);
            u32 v0 = pk2(fmaxf(pb0.x + g0.x, 0.f), fmaxf(pb0.y + g0.y, 0.f));
            u32 v1 = pk2(fmaxf(pb0.z + g0.z, 0.f), fmaxf(pb0.w + g0.w, 0.f));
            u32 v2 = pk2(fmaxf(pb1.x + g1.x, 0.f), fmaxf(pb1.y + g1.y, 0.f));
            u32 v3 = pk2(fmaxf(pb1.z + g1.z, 0.f), fmaxf(pb1.w + g1.w, 0.f));
            *(uint4*)ast2 = make_uint4(v0, v1, v2, v3);
        }

        __syncthreads();

        // ---- prefetch next-k hj (flies during MFMA cluster) ----
        if (k0 + 64 < D2) {
            pa0 = *(const float4*)(hjbase + k0 + 64 + o1);
            pa1 = *(const float4*)(hjbase + k0 + 64 + o1 + 4);
            pb0 = *(const float4*)(hjbase + k0 + 64 + o2);
            pb1 = *(const float4*)(hjbase + k0 + 64 + o2 + 4);
        }

        // ---- fragments + MFMA, two K=32 sub-steps ----
#pragma unroll
        for (int kk = 0; kk < 2; ++kk) {
            short8 af[4], bfr[4];
#pragma unroll
            for (int mt = 0; mt < 4; ++mt)
                af[mt] = *(const short8*)&Asb[(((wm * 64 + mt * 16 + lr) * 64) + kk * 32 + lq * 8) ^ rswz];
#pragma unroll
            for (int nt = 0; nt < 4; ++nt)
                bfr[nt] = *(const short8*)&Bsb[(((wn * 64 + nt * 16 + lr) * 64) + kk * 32 + lq * 8) ^ rswz];
            __builtin_amdgcn_s_setprio(1);
#pragma unroll
            for (int mt = 0; mt < 4; ++mt)
#pragma unroll
                for (int nt = 0; nt < 4; ++nt)
                    acc[mt][nt] = __builtin_amdgcn_mfma_f32_16x16x32_bf16(
                        af[mt], bfr[nt], acc[mt][nt], 0, 0, 0);
            __builtin_amdgcn_s_setprio(0);
        }
    }

    // ---- epilogue ----
    float bias[4];
#pragma unroll
    for (int nt = 0; nt < 4; ++nt)
        bias[nt] = br2[n0 + wn * 64 + nt * 16 + lr];

#pragma unroll
    for (int mt = 0; mt < 4; ++mt) {
        const int mbase = wm * 64 + mt * 16 + lq * 4;
#pragma unroll
        for (int r = 0; r < 4; ++r) {
            const int mm = mbase + r;
            const int sel = mm >> 6, j = mm & 63;
            float* orow = out + (((size_t)(bi0 + sel) * 64 + j) * Dm) + n0 + wn * 64;
#pragma unroll
            for (int nt = 0; nt < 4; ++nt)
                orow[nt * 16 + lr] = acc[mt][nt][r] + bias[nt];
        }
    }
}

// ---------------------------------------------------------------------------
extern "C" void kernel_launch(void* const* d_in, const int* in_sizes, int n_in,
                              void* d_out, int out_size, void* d_ws, size_t ws_size,
                              hipStream_t stream) {
    const float* h    = (const float*)d_in[0];
    const int*   span = (const int*)  d_in[1];
    const float* Ws1  = (const float*)d_in[2];
    const float* bs1  = (const float*)d_in[3];
    const float* Ws2  = (const float*)d_in[4];
    const float* bs2  = (const float*)d_in[5];
    const float* We1  = (const float*)d_in[6];
    const float* be1  = (const float*)d_in[7];
    const float* We2  = (const float*)d_in[8];
    const float* be2  = (const float*)d_in[9];
    const float* Wo   = (const float*)d_in[10];
    const float* bo   = (const float*)d_in[11];
    const float* Wr1  = (const float*)d_in[12];
    const float* br1  = (const float*)d_in[13];
    const float* Wr2  = (const float*)d_in[14];
    const float* br2  = (const float*)d_in[15];
    float* out = (float*)d_out;

    dim3 blk(256);
    const size_t REQUIRED = (size_t)120 << 20;

    if (ws_size >= REQUIRED) {
        // ---------------- split-bf16 MFMA path ----------------
        char* W = (char*)d_ws;
        size_t off = 0;
        auto alloc = [&](size_t bytes) { char* q = W + off; off += bytes; return q; };

        u16* W1t_h = (u16*)alloc((size_t)2 * 2048 * 1024 * 2);
        u16* W1t_l = (u16*)alloc((size_t)2 * 2048 * 1024 * 2);
        u16* W2t_h = (u16*)alloc((size_t)2 * 1024 * 2048 * 2);
        u16* W2t_l = (u16*)alloc((size_t)2 * 1024 * 2048 * 2);
        u16* Wot_h = (u16*)alloc((size_t)2048 * 2048 * 2);
        u16* Wot_l = (u16*)alloc((size_t)2048 * 2048 * 2);
        u16* Wr1t_h = (u16*)alloc((size_t)2 * 2048 * 2048 * 2);
        u16* Wr1t_l = (u16*)alloc((size_t)2 * 2048 * 2048 * 2);
        u16* Wr2t_h = (u16*)alloc((size_t)1024 * 2048 * 2);
        u16* gs_h  = (u16*)alloc((size_t)2 * 512 * 1024 * 2);
        u16* gs_l  = (u16*)alloc((size_t)2 * 512 * 1024 * 2);
        u16* t1_h  = (u16*)alloc((size_t)2 * 512 * 2048 * 2);
        u16* t1_l  = (u16*)alloc((size_t)2 * 512 * 2048 * 2);
        u16* cat_h = (u16*)alloc((size_t)512 * 2048 * 2);
        u16* cat_l = (u16*)alloc((size_t)512 * 2048 * 2);
        u16* ent_h = (u16*)alloc((size_t)512 * 2048 * 2);
        u16* ent_l = (u16*)alloc((size_t)512 * 2048 * 2);
        float* hif = (float*)alloc((size_t)512 * 2048 * 4);
        float* hjf = (float*)alloc((size_t)512 * 2048 * 4);

        TransJobs J;
        J.src[0] = Ws1;  J.dh[0] = W1t_h;                J.dl[0] = W1t_l;                J.K[0] = 1024; J.N[0] = 2048; J.tiles[0] = 512;
        J.src[1] = We1;  J.dh[1] = W1t_h + 2048 * 1024;  J.dl[1] = W1t_l + 2048 * 1024;  J.K[1] = 1024; J.N[1] = 2048; J.tiles[1] = 512;
        J.src[2] = Ws2;  J.dh[2] = W2t_h;                J.dl[2] = W2t_l;                J.K[2] = 2048; J.N[2] = 1024; J.tiles[2] = 512;
        J.src[3] = We2;  J.dh[3] = W2t_h + 1024 * 2048;  J.dl[3] = W2t_l + 1024 * 2048;  J.K[3] = 2048; J.N[3] = 1024; J.tiles[3] = 512;
        J.src[4] = Wo;   J.dh[4] = Wot_h;                J.dl[4] = Wot_l;                J.K[4] = 2048; J.N[4] = 2048; J.tiles[4] = 1024;
        J.src[5] = Wr1;  J.dh[5] = Wr1t_h;               J.dl[5] = Wr1t_l;               J.K[5] = 2048; J.N[5] = 2048; J.tiles[5] = 1024;
        J.src[6] = Wr1 + (size_t)2048 * 2048;
                         J.dh[6] = Wr1t_h + (size_t)2048 * 2048; J.dl[6] = Wr1t_l + (size_t)2048 * 2048;
                                                                          J.K[6] = 2048; J.N[6] = 2048; J.tiles[6] = 1024;
        J.src[7] = Wr2;  J.dh[7] = Wr2t_h;               J.dl[7] = nullptr;              J.K[7] = 2048; J.N[7] = 1024; J.tiles[7] = 512;
        transpose_split<<<dim3(5632), blk, 0, stream>>>(J);

        gather_split<<<dim3(512, 2), blk, 0, stream>>>(h, span, gs_h, gs_l);

        GemmP p1 = {};
        p1.ah0 = gs_h; p1.ah1 = gs_h + 512 * 1024;
        p1.al0 = gs_l; p1.al1 = gs_l + 512 * 1024;
        p1.wh0 = W1t_h; p1.wh1 = W1t_h + 2048 * 1024;
        p1.wl0 = W1t_l; p1.wl1 = W1t_l + 2048 * 1024;
        p1.b0 = bs1; p1.b1 = be1;
        p1.oh0 = t1_h; p1.oh1 = t1_h + 512 * 2048;
        p1.ol0 = t1_l; p1.ol1 = t1_l + 512 * 2048;
        p1.K = 1024; p1.ldc = 2048; p1.coloff1 = 0;
        gemm_split<true, true, true><<<dim3(8, 32, 2), blk, 0, stream>>>(p1);

        GemmP p2 = {};
        p2.ah0 = t1_h; p2.ah1 = t1_h + 512 * 2048;
        p2.al0 = t1_l; p2.al1 = t1_l + 512 * 2048;
        p2.wh0 = W2t_h; p2.wh1 = W2t_h + 1024 * 2048;
        p2.wl0 = W2t_l; p2.wl1 = W2t_l + 1024 * 2048;
        p2.b0 = bs2; p2.b1 = be2;
        p2.oh0 = cat_h; p2.oh1 = cat_h;
        p2.ol0 = cat_l; p2.ol1 = cat_l;
        p2.K = 2048; p2.ldc = 2048; p2.coloff1 = 1024;
        gemm_split<true, true, true><<<dim3(8, 16, 2), blk, 0, stream>>>(p2);

        GemmP p3 = {};
        p3.ah0 = cat_h; p3.al0 = cat_l;
        p3.wh0 = Wot_h; p3.wl0 = Wot_l;
        p3.b0 = bo;
        p3.oh0 = ent_h; p3.ol0 = ent_l;
        p3.K = 2048; p3.ldc = 2048; p3.coloff1 = 0;
        gemm_split<false, true, true><<<dim3(8, 32, 1), blk, 0, stream>>>(p3);

        GemmP p4 = {};
        p4.ah0 = ent_h; p4.ah1 = ent_h;
        p4.al0 = ent_l; p4.al1 = ent_l;
        p4.wh0 = Wr1t_h; p4.wh1 = Wr1t_h + (size_t)2048 * 2048;
        p4.wl0 = Wr1t_l; p4.wl1 = Wr1t_l + (size_t)2048 * 2048;
        p4.of0 = hif; p4.of1 = hjf;
        p4.K = 2048; p4.ldc = 2048; p4.coloff1 = 0;
        gemm_split<false, false, false><<<dim3(8, 32, 2), blk, 0, stream>>>(p4);

        big_mfma<<<dim3(256, 4), dim3(512), 0, stream>>>(hif, hjf, br1, Wr2t_h, br2, out);
    } else {
        // ---------------- fp32 fallback (round-1 structure) ----------------
        u16* Wt = (u16*)d_ws;                               // 4 MB
        float* ws  = (float*)((char*)d_ws + (size_t)Dm * D2 * 2);
        float* gs  = ws;
        float* ge  = gs  + 512 * Dm;
        float* t1  = ge  + 512 * Dm;
        float* cat = t1  + 512 * D2;
        float* ent = cat + 512 * D2;
        float* hi  = ent + 512 * D2;
        float* hj  = hi  + 512 * D2;

        TransJobs J = {};
        J.src[0] = Wr2; J.dh[0] = Wt; J.dl[0] = nullptr;
        J.K[0] = 2048; J.N[0] = 1024; J.tiles[0] = 512;
        transpose_split<<<dim3(512), blk, 0, stream>>>(J);

        gather_rows<<<dim3(512, 2), blk, 0, stream>>>(h, span, gs, ge);
        gemm_f32<true,  true><<<dim3(8, 32), blk, 0, stream>>>(gs, Dm, Ws1, D2, bs1, t1, D2, Dm);
        gemm_f32<true,  true><<<dim3(8, 16), blk, 0, stream>>>(t1, D2, Ws2, Dm, bs2, cat, D2, D2);
        gemm_f32<true,  true><<<dim3(8, 32), blk, 0, stream>>>(ge, Dm, We1, D2, be1, t1, D2, Dm);
        gemm_f32<true,  true><<<dim3(8, 16), blk, 0, stream>>>(t1, D2, We2, Dm, be2, cat + Dm, D2, D2);
        gemm_f32<false, true><<<dim3(8, 32), blk, 0, stream>>>(cat, D2, Wo, D2, bo, ent, D2, D2);
        gemm_f32<false, false><<<dim3(8, 32), blk, 0, stream>>>(ent, D2, Wr1, D2, nullptr, hi, D2, D2);
        gemm_f32<false, false><<<dim3(8, 32), blk, 0, stream>>>(ent, D2, Wr1 + (size_t)D2 * D2, D2, nullptr, hj, D2, D2);
        big_mfma<<<dim3(256, 4), dim3(512), 0, stream>>>(hi, hj, br1, Wt, br2, out);
    }
}

// Round 4
// 503.396 us; speedup vs baseline: 1.3021x; 1.3021x over previous
//
#include <hip/hip_runtime.h>
#include <hip/hip_bf16.h>

// Problem constants: B=8, L=512, N=64, D=1024
constexpr int Lseq = 512;
constexpr int Nsp  = 64;
constexpr int Dm   = 1024;   // D
constexpr int D2   = 2048;   // 2D

typedef __attribute__((ext_vector_type(8))) short short8;
typedef __attribute__((ext_vector_type(4))) float floatx4;
typedef unsigned short u16;
typedef unsigned int   u32;

__device__ __forceinline__ u32 f2bf(float x) {
    u32 u = __float_as_uint(x);
    return (u + 0x7fffu + ((u >> 16) & 1u)) >> 16;   // RNE
}
__device__ __forceinline__ float bf2f(u32 hbits) {
    return __uint_as_float(hbits << 16);
}
__device__ __forceinline__ u32 pk2(float x0, float x1) {
    __hip_bfloat162 bb = __float22bfloat162_rn(make_float2(x0, x1));
    u32 r; __builtin_memcpy(&r, &bb, 4); return r;
}

// XOR swizzle for 64B-row LDS tiles (32 u16 per row): spread 16 same-chunk
// rows over all 8 bank quads.  u16-index form: idx ^= ((row>>1)&3)<<3.
// (big_mfma BK=32 tiles; measured 0 bank conflicts, R2.)
__device__ __forceinline__ int swz_idx(int row, int chunk8) {
    return (row * 32 + chunk8 * 8) ^ (((row >> 1) & 3) << 3);
}

// ---------------------------------------------------------------------------
// Gather h rows at span indices, emitting hi/lo bf16 split. grid (512,2).
// ---------------------------------------------------------------------------
__global__ __launch_bounds__(256)
void gather_split(const float* __restrict__ h, const int* __restrict__ span,
                  u16* __restrict__ g_hi, u16* __restrict__ g_lo)
{
    const int row = blockIdx.x, which = blockIdx.y;
    const int b = row >> 6;
    const int idx = span[row * 2 + which];
    const float4* src = (const float4*)(h + ((size_t)b * Lseq + idx) * Dm);
    float4 v = src[threadIdx.x];
    u32 h01 = pk2(v.x, v.y), h23 = pk2(v.z, v.w);
    u32 l01 = pk2(v.x - bf2f(h01 & 0xffffu), v.y - bf2f(h01 >> 16));
    u32 l23 = pk2(v.z - bf2f(h23 & 0xffffu), v.w - bf2f(h23 >> 16));
    size_t off = ((size_t)which * 512 + row) * Dm + (size_t)threadIdx.x * 4;
    *(uint2*)(g_hi + off) = make_uint2(h01, h23);
    *(uint2*)(g_lo + off) = make_uint2(l01, l23);
}

// Plain fp32 gather (fallback path)
__global__ __launch_bounds__(256)
void gather_rows(const float* __restrict__ h, const int* __restrict__ span,
                 float* __restrict__ gs, float* __restrict__ ge)
{
    const int row = blockIdx.x, which = blockIdx.y;
    const int b = row >> 6;
    const int idx = span[row * 2 + which];
    const float4* src = (const float4*)(h + ((size_t)b * Lseq + idx) * Dm);
    float4* dst = (float4*)((which ? ge : gs) + (size_t)row * Dm);
    dst[threadIdx.x] = src[threadIdx.x];
}

// ---------------------------------------------------------------------------
// Batched weight transpose+split: W[k][n] fp32 -> Wt_hi/lo[n][k] bf16.
// ---------------------------------------------------------------------------
struct TransJobs {
    const float* src[8];
    u16* dh[8];
    u16* dl[8];
    int K[8], N[8], tiles[8];
};

__global__ __launch_bounds__(256)
void transpose_split(TransJobs J)
{
    __shared__ float T[64][65];
    int b = blockIdx.x, j = 0;
    while (b >= J.tiles[j]) { b -= J.tiles[j]; ++j; }
    const float* src = J.src[j];
    const int K = J.K[j], N = J.N[j];
    const int tk = K >> 6;
    const int k0 = (b % tk) * 64, n0 = (b / tk) * 64;
    const int t = threadIdx.x, c = t & 63, r4 = t >> 6;
#pragma unroll
    for (int s = 0; s < 16; ++s) {
        int r = r4 * 16 + s;
        T[r][c] = src[(size_t)(k0 + r) * N + n0 + c];
    }
    __syncthreads();
    u16* dh = J.dh[j];
    u16* dl = J.dl[j];
#pragma unroll
    for (int s = 0; s < 16; ++s) {
        int n = r4 * 16 + s;
        float v = T[c][n];
        u32 hv = f2bf(v);
        dh[(size_t)(n0 + n) * K + k0 + c] = (u16)hv;
        if (dl) dl[(size_t)(n0 + n) * K + k0 + c] = (u16)f2bf(v - bf2f(hv));
    }
}

// ---------------------------------------------------------------------------
// Split-bf16 MFMA GEMM: C = act(A @ W + bias), A as hi/lo bf16 [M][K],
// W pre-transposed+split Wt_hi/lo[n][k]. Tile 64x64, K-step 64 (halves the
// barrier-drain count). 4 waves; wave w owns rows [w*16, w*16+16). 3 MFMAs
// per tile pair. LDS 128B-row tiles with chunk^(row&7) swizzle both sides.
// ---------------------------------------------------------------------------
struct GemmP {
    const u16 *ah0, *ah1, *al0, *al1;
    const u16 *wh0, *wh1, *wl0, *wl1;
    const float *b0, *b1;
    float *of0, *of1;
    u16 *oh0, *oh1, *ol0, *ol1;
    int K, ldc, coloff1;
};

template<bool RELU, bool BIAS, bool SPLIT_OUT>
__global__ __launch_bounds__(256)
void gemm_split(GemmP P)
{
    __shared__ __align__(16) u16 As_h[64 * 64];
    __shared__ __align__(16) u16 As_l[64 * 64];
    __shared__ __align__(16) u16 Bs_h[64 * 64];
    __shared__ __align__(16) u16 Bs_l[64 * 64];

    const int tid = threadIdx.x, w = tid >> 6, l = tid & 63;
    const int lr = l & 15, lq = l >> 4;
    const int z = blockIdx.z;
    const int m0 = blockIdx.x * 64, n0 = blockIdx.y * 64;
    const int K = P.K;

    const u16* ah = z ? P.ah1 : P.ah0;
    const u16* al = z ? P.al1 : P.al0;
    const u16* wh = z ? P.wh1 : P.wh0;
    const u16* wl = z ? P.wl1 : P.wl0;

    // Each wave stages one 64x64 bf16 tile (8 KB) via 8 global_load_lds.
    const u16* src; u16* ldst;
    if      (w == 0) { src = ah + (size_t)m0 * K; ldst = As_h; }
    else if (w == 1) { src = al + (size_t)m0 * K; ldst = As_l; }
    else if (w == 2) { src = wh + (size_t)n0 * K; ldst = Bs_h; }
    else             { src = wl + (size_t)n0 * K; ldst = Bs_l; }
    // pre-swizzled source chunk: linear LDS write lands swizzled layout
    const int schunk = (l & 7) ^ ((l >> 3) & 7);
    const u16* sl = src + (size_t)(l >> 3) * K + (size_t)schunk * 8;

    // fragment-read swizzle: row&7 == lr&7 for rows x*16+lr
    const int rswz = (lr & 7) << 3;

    floatx4 acc[4];
#pragma unroll
    for (int nt = 0; nt < 4; ++nt) acc[nt] = (floatx4){0.f, 0.f, 0.f, 0.f};

    for (int k0 = 0; k0 < K; k0 += 64) {
        __syncthreads();
#pragma unroll
        for (int i = 0; i < 8; ++i)
            __builtin_amdgcn_global_load_lds(
                (const __attribute__((address_space(1))) u32*)(sl + (size_t)i * 8 * K + k0),
                (__attribute__((address_space(3))) u32*)(ldst + i * 512), 16, 0, 0);
        __syncthreads();

#pragma unroll
        for (int kk = 0; kk < 2; ++kk) {
            const int ar = (((w * 16 + lr) * 64) + kk * 32 + lq * 8) ^ rswz;
            short8 fah = *(const short8*)&As_h[ar];
            short8 fal = *(const short8*)&As_l[ar];
#pragma unroll
            for (int nt = 0; nt < 4; ++nt) {
                const int brd = (((nt * 16 + lr) * 64) + kk * 32 + lq * 8) ^ rswz;
                short8 fbh = *(const short8*)&Bs_h[brd];
                short8 fbl = *(const short8*)&Bs_l[brd];
                acc[nt] = __builtin_amdgcn_mfma_f32_16x16x32_bf16(fah, fbh, acc[nt], 0, 0, 0);
                acc[nt] = __builtin_amdgcn_mfma_f32_16x16x32_bf16(fal, fbh, acc[nt], 0, 0, 0);
                acc[nt] = __builtin_amdgcn_mfma_f32_16x16x32_bf16(fah, fbl, acc[nt], 0, 0, 0);
            }
        }
    }

    const float* bias = z ? P.b1 : P.b0;
    const int colb = n0 + (z ? P.coloff1 : 0);
    float bv[4];
    if (BIAS) {
#pragma unroll
        for (int nt = 0; nt < 4; ++nt) bv[nt] = bias[n0 + nt * 16 + lr];
    }
#pragma unroll
    for (int nt = 0; nt < 4; ++nt) {
#pragma unroll
        for (int r = 0; r < 4; ++r) {
            float x = acc[nt][r];
            if (BIAS) x += bv[nt];
            if (RELU) x = fmaxf(x, 0.f);
            const int m = m0 + w * 16 + lq * 4 + r;
            const size_t oidx = (size_t)m * P.ldc + colb + nt * 16 + lr;
            if (SPLIT_OUT) {
                u16* oh = z ? P.oh1 : P.oh0;
                u16* ol = z ? P.ol1 : P.ol0;
                u32 hv = f2bf(x);
                oh[oidx] = (u16)hv;
                ol[oidx] = (u16)f2bf(x - bf2f(hv));
            } else {
                float* of = z ? P.of1 : P.of0;
                of[oidx] = x;
            }
        }
    }
}

// ---------------------------------------------------------------------------
// fp32 GEMM fallback (round-1) for small layers if ws is too small.
// ---------------------------------------------------------------------------
template<bool RELU, bool BIAS>
__global__ __launch_bounds__(256)
void gemm_f32(const float* __restrict__ A, int lda,
              const float* __restrict__ W, int ldw,
              const float* __restrict__ bias,
              float* __restrict__ C, int ldc, int K)
{
    __shared__ float As[16][64];
    __shared__ float Ws[16][64];
    const int tid = threadIdx.x;
    const int tx = tid & 15, ty = tid >> 4;
    const int m0 = blockIdx.x * 64, n0 = blockIdx.y * 64;
    const int la_c = tid & 15, la_r = tid >> 4;
    const int lw_n = tid & 63, lw_k = tid >> 6;
    float acc[4][4] = {};
    for (int k0 = 0; k0 < K; k0 += 16) {
#pragma unroll
        for (int s = 0; s < 4; ++s) {
            int m = la_r + 16 * s;
            As[la_c][m] = A[(size_t)(m0 + m) * lda + k0 + la_c];
        }
#pragma unroll
        for (int s = 0; s < 4; ++s) {
            int k = lw_k + 4 * s;
            Ws[k][lw_n] = W[(size_t)(k0 + k) * ldw + n0 + lw_n];
        }
        __syncthreads();
#pragma unroll
        for (int kk = 0; kk < 16; ++kk) {
            float a4[4], w4[4];
            *(float4*)a4 = *(const float4*)&As[kk][ty * 4];
            *(float4*)w4 = *(const float4*)&Ws[kk][tx * 4];
#pragma unroll
            for (int i = 0; i < 4; ++i)
#pragma unroll
                for (int j = 0; j < 4; ++j)
                    acc[i][j] = fmaf(a4[i], w4[j], acc[i][j]);
        }
        __syncthreads();
    }
#pragma unroll
    for (int i = 0; i < 4; ++i) {
        float4 v; float* vp = (float*)&v;
#pragma unroll
        for (int j = 0; j < 4; ++j) {
            float x = acc[i][j];
            if (BIAS) x += bias[n0 + tx * 4 + j];
            if (RELU) x = fmaxf(x, 0.f);
            vp[j] = x;
        }
        *(float4*)&C[(size_t)(m0 + ty * 4 + i) * ldc + n0 + tx * 4] = v;
    }
}

// ---------------------------------------------------------------------------
// Final GEMM via bf16 MFMA; hidden = relu(hi ⊕ hj + br1) built on the fly.
// 512 threads, 8 waves (wm 0..1 × wn 0..3), tile 128(M)x256(N), grid (256,4).
// R2-proven version: K-step 32, [row][32] tiles, XOR swizzle
// idx ^= ((row>>1)&3)<<3 on BOTH sides (A: per-lane ds_write + read;
// B: pre-swizzled global source + read).  B gload_lds before A-build VALU.
// NOTE: BK=64 here spills (reg budget 128 @ launch_bounds(512,4)) — R3
// measured 489 MiB scratch writes, 2x dur. Do not raise BK without
// raising the register budget.
// ---------------------------------------------------------------------------
__global__ __launch_bounds__(512, 4)
void big_mfma(const float* __restrict__ hi, const float* __restrict__ hj,
              const float* __restrict__ br1, const u16* __restrict__ Wt,
              const float* __restrict__ br2, float* __restrict__ out)
{
    __shared__ float hiP[2][D2];                     // 16 KB
    __shared__ __align__(16) u16 Asb[128 * 32];      // swizzled [128][32], 8 KB
    __shared__ __align__(16) u16 Bsb[256 * 32];      // swizzled [256][32], 16 KB

    const int tid = threadIdx.x;
    const int p = blockIdx.x, n0 = blockIdx.y * 256;
    const int b = p >> 5, bi0 = p * 2;

    // A-build assignment: one (row, k-chunk) per thread.
    const int rowA = tid >> 2, kq = tid & 3;
    const int selA = rowA >> 6, jA = rowA & 63;
    const float* hjrow = hj + ((size_t)b * 64 + jA) * D2 + kq * 8;
    u16* astore = Asb + swz_idx(rowA, kq);
    const float* hip = hiP[selA] + kq * 8;

    // Prefetch hj chunk for k0=0 (in flight during hiP staging).
    float4 pf0 = *(const float4*)(hjrow);
    float4 pf1 = *(const float4*)(hjrow + 4);

    // hiP = hi(+pair) + br1  (1024 float4 over 512 threads)
    {
        const float4* h0 = (const float4*)(hi + (size_t)bi0 * D2);
        const float4* h1 = (const float4*)(hi + (size_t)(bi0 + 1) * D2);
        const float4* br = (const float4*)br1;
        float4* d0 = (float4*)hiP[0];
        float4* d1 = (float4*)hiP[1];
        const int v = tid;   // 512 threads, 512 float4 per row
        float4 bb = br[v];
        float4 a = h0[v];
        a.x += bb.x; a.y += bb.y; a.z += bb.z; a.w += bb.w;
        d0[v] = a;
        float4 c = h1[v];
        c.x += bb.x; c.y += bb.y; c.z += bb.z; c.w += bb.w;
        d1[v] = c;
    }

    const int w = tid >> 6, l = tid & 63;
    const int wm = w & 1, wn = w >> 1;
    const int lr = l & 15, lq = l >> 4;
    const int rswz = ((lr >> 1) & 3) << 3;

    // B source: pre-swizzled chunk so linear gload write == swizzled layout.
    const int schunk = (l & 3) ^ ((l >> 3) & 3);

    floatx4 acc[4][4];
#pragma unroll
    for (int mt = 0; mt < 4; ++mt)
#pragma unroll
        for (int nt = 0; nt < 4; ++nt)
            acc[mt][nt] = (floatx4){0.f, 0.f, 0.f, 0.f};

    for (int k0 = 0; k0 < D2; k0 += 32) {
        __syncthreads();

        // ---- B tile: async bf16 stage first (hides under A-build) ----
#pragma unroll
        for (int c = 0; c < 2; ++c) {
            const u16* g = Wt + (size_t)(n0 + w * 32 + c * 16 + (l >> 2)) * D2
                              + k0 + schunk * 8;
            u16* lp = Bsb + (w * 32 + c * 16) * 32;
            __builtin_amdgcn_global_load_lds(
                (const __attribute__((address_space(1))) u32*)g,
                (__attribute__((address_space(3))) u32*)lp, 16, 0, 0);
        }

        // ---- A tile: relu(hi' + hj) -> bf16, swizzled store ----
        {
            float4 h0 = *(const float4*)(hip + k0);
            float4 h1 = *(const float4*)(hip + k0 + 4);
            u32 u0 = pk2(fmaxf(pf0.x + h0.x, 0.f), fmaxf(pf0.y + h0.y, 0.f));
            u32 u1 = pk2(fmaxf(pf0.z + h0.z, 0.f), fmaxf(pf0.w + h0.w, 0.f));
            u32 u2 = pk2(fmaxf(pf1.x + h1.x, 0.f), fmaxf(pf1.y + h1.y, 0.f));
            u32 u3 = pk2(fmaxf(pf1.z + h1.z, 0.f), fmaxf(pf1.w + h1.w, 0.f));
            *(uint4*)astore = make_uint4(u0, u1, u2, u3);
        }

        __syncthreads();

        // ---- prefetch next-k hj (flies during MFMA cluster) ----
        if (k0 + 32 < D2) {
            pf0 = *(const float4*)(hjrow + k0 + 32);
            pf1 = *(const float4*)(hjrow + k0 + 36);
        }

        // ---- fragments + MFMA ----
        short8 af[4], bfr[4];
#pragma unroll
        for (int mt = 0; mt < 4; ++mt)
            af[mt] = *(const short8*)&Asb[(((wm * 64 + mt * 16 + lr) * 32) + lq * 8) ^ rswz];
#pragma unroll
        for (int nt = 0; nt < 4; ++nt)
            bfr[nt] = *(const short8*)&Bsb[(((wn * 64 + nt * 16 + lr) * 32) + lq * 8) ^ rswz];
        __builtin_amdgcn_s_setprio(1);
#pragma unroll
        for (int mt = 0; mt < 4; ++mt)
#pragma unroll
            for (int nt = 0; nt < 4; ++nt)
                acc[mt][nt] = __builtin_amdgcn_mfma_f32_16x16x32_bf16(
                    af[mt], bfr[nt], acc[mt][nt], 0, 0, 0);
        __builtin_amdgcn_s_setprio(0);
    }

    // ---- epilogue ----
    float bias[4];
#pragma unroll
    for (int nt = 0; nt < 4; ++nt)
        bias[nt] = br2[n0 + wn * 64 + nt * 16 + lr];

#pragma unroll
    for (int mt = 0; mt < 4; ++mt) {
        const int mbase = wm * 64 + mt * 16 + lq * 4;
#pragma unroll
        for (int r = 0; r < 4; ++r) {
            const int mm = mbase + r;
            const int sel = mm >> 6, j = mm & 63;
            float* orow = out + (((size_t)(bi0 + sel) * 64 + j) * Dm) + n0 + wn * 64;
#pragma unroll
            for (int nt = 0; nt < 4; ++nt)
                orow[nt * 16 + lr] = acc[mt][nt][r] + bias[nt];
        }
    }
}

// ---------------------------------------------------------------------------
extern "C" void kernel_launch(void* const* d_in, const int* in_sizes, int n_in,
                              void* d_out, int out_size, void* d_ws, size_t ws_size,
                              hipStream_t stream) {
    const float* h    = (const float*)d_in[0];
    const int*   span = (const int*)  d_in[1];
    const float* Ws1  = (const float*)d_in[2];
    const float* bs1  = (const float*)d_in[3];
    const float* Ws2  = (const float*)d_in[4];
    const float* bs2  = (const float*)d_in[5];
    const float* We1  = (const float*)d_in[6];
    const float* be1  = (const float*)d_in[7];
    const float* We2  = (const float*)d_in[8];
    const float* be2  = (const float*)d_in[9];
    const float* Wo   = (const float*)d_in[10];
    const float* bo   = (const float*)d_in[11];
    const float* Wr1  = (const float*)d_in[12];
    const float* br1  = (const float*)d_in[13];
    const float* Wr2  = (const float*)d_in[14];
    const float* br2  = (const float*)d_in[15];
    float* out = (float*)d_out;

    dim3 blk(256);
    const size_t REQUIRED = (size_t)120 << 20;

    if (ws_size >= REQUIRED) {
        // ---------------- split-bf16 MFMA path ----------------
        char* W = (char*)d_ws;
        size_t off = 0;
        auto alloc = [&](size_t bytes) { char* q = W + off; off += bytes; return q; };

        u16* W1t_h = (u16*)alloc((size_t)2 * 2048 * 1024 * 2);
        u16* W1t_l = (u16*)alloc((size_t)2 * 2048 * 1024 * 2);
        u16* W2t_h = (u16*)alloc((size_t)2 * 1024 * 2048 * 2);
        u16* W2t_l = (u16*)alloc((size_t)2 * 1024 * 2048 * 2);
        u16* Wot_h = (u16*)alloc((size_t)2048 * 2048 * 2);
        u16* Wot_l = (u16*)alloc((size_t)2048 * 2048 * 2);
        u16* Wr1t_h = (u16*)alloc((size_t)2 * 2048 * 2048 * 2);
        u16* Wr1t_l = (u16*)alloc((size_t)2 * 2048 * 2048 * 2);
        u16* Wr2t_h = (u16*)alloc((size_t)1024 * 2048 * 2);
        u16* gs_h  = (u16*)alloc((size_t)2 * 512 * 1024 * 2);
        u16* gs_l  = (u16*)alloc((size_t)2 * 512 * 1024 * 2);
        u16* t1_h  = (u16*)alloc((size_t)2 * 512 * 2048 * 2);
        u16* t1_l  = (u16*)alloc((size_t)2 * 512 * 2048 * 2);
        u16* cat_h = (u16*)alloc((size_t)512 * 2048 * 2);
        u16* cat_l = (u16*)alloc((size_t)512 * 2048 * 2);
        u16* ent_h = (u16*)alloc((size_t)512 * 2048 * 2);
        u16* ent_l = (u16*)alloc((size_t)512 * 2048 * 2);
        float* hif = (float*)alloc((size_t)512 * 2048 * 4);
        float* hjf = (float*)alloc((size_t)512 * 2048 * 4);

        TransJobs J;
        J.src[0] = Ws1;  J.dh[0] = W1t_h;                J.dl[0] = W1t_l;                J.K[0] = 1024; J.N[0] = 2048; J.tiles[0] = 512;
        J.src[1] = We1;  J.dh[1] = W1t_h + 2048 * 1024;  J.dl[1] = W1t_l + 2048 * 1024;  J.K[1] = 1024; J.N[1] = 2048; J.tiles[1] = 512;
        J.src[2] = Ws2;  J.dh[2] = W2t_h;                J.dl[2] = W2t_l;                J.K[2] = 2048; J.N[2] = 1024; J.tiles[2] = 512;
        J.src[3] = We2;  J.dh[3] = W2t_h + 1024 * 2048;  J.dl[3] = W2t_l + 1024 * 2048;  J.K[3] = 2048; J.N[3] = 1024; J.tiles[3] = 512;
        J.src[4] = Wo;   J.dh[4] = Wot_h;                J.dl[4] = Wot_l;                J.K[4] = 2048; J.N[4] = 2048; J.tiles[4] = 1024;
        J.src[5] = Wr1;  J.dh[5] = Wr1t_h;               J.dl[5] = Wr1t_l;               J.K[5] = 2048; J.N[5] = 2048; J.tiles[5] = 1024;
        J.src[6] = Wr1 + (size_t)2048 * 2048;
                         J.dh[6] = Wr1t_h + (size_t)2048 * 2048; J.dl[6] = Wr1t_l + (size_t)2048 * 2048;
                                                                          J.K[6] = 2048; J.N[6] = 2048; J.tiles[6] = 1024;
        J.src[7] = Wr2;  J.dh[7] = Wr2t_h;               J.dl[7] = nullptr;              J.K[7] = 2048; J.N[7] = 1024; J.tiles[7] = 512;
        transpose_split<<<dim3(5632), blk, 0, stream>>>(J);

        gather_split<<<dim3(512, 2), blk, 0, stream>>>(h, span, gs_h, gs_l);

        GemmP p1 = {};
        p1.ah0 = gs_h; p1.ah1 = gs_h + 512 * 1024;
        p1.al0 = gs_l; p1.al1 = gs_l + 512 * 1024;
        p1.wh0 = W1t_h; p1.wh1 = W1t_h + 2048 * 1024;
        p1.wl0 = W1t_l; p1.wl1 = W1t_l + 2048 * 1024;
        p1.b0 = bs1; p1.b1 = be1;
        p1.oh0 = t1_h; p1.oh1 = t1_h + 512 * 2048;
        p1.ol0 = t1_l; p1.ol1 = t1_l + 512 * 2048;
        p1.K = 1024; p1.ldc = 2048; p1.coloff1 = 0;
        gemm_split<true, true, true><<<dim3(8, 32, 2), blk, 0, stream>>>(p1);

        GemmP p2 = {};
        p2.ah0 = t1_h; p2.ah1 = t1_h + 512 * 2048;
        p2.al0 = t1_l; p2.al1 = t1_l + 512 * 2048;
        p2.wh0 = W2t_h; p2.wh1 = W2t_h + 1024 * 2048;
        p2.wl0 = W2t_l; p2.wl1 = W2t_l + 1024 * 2048;
        p2.b0 = bs2; p2.b1 = be2;
        p2.oh0 = cat_h; p2.oh1 = cat_h;
        p2.ol0 = cat_l; p2.ol1 = cat_l;
        p2.K = 2048; p2.ldc = 2048; p2.coloff1 = 1024;
        gemm_split<true, true, true><<<dim3(8, 16, 2), blk, 0, stream>>>(p2);

        GemmP p3 = {};
        p3.ah0 = cat_h; p3.al0 = cat_l;
        p3.wh0 = Wot_h; p3.wl0 = Wot_l;
        p3.b0 = bo;
        p3.oh0 = ent_h; p3.ol0 = ent_l;
        p3.K = 2048; p3.ldc = 2048; p3.coloff1 = 0;
        gemm_split<false, true, true><<<dim3(8, 32, 1), blk, 0, stream>>>(p3);

        GemmP p4 = {};
        p4.ah0 = ent_h; p4.ah1 = ent_h;
        p4.al0 = ent_l; p4.al1 = ent_l;
        p4.wh0 = Wr1t_h; p4.wh1 = Wr1t_h + (size_t)2048 * 2048;
        p4.wl0 = Wr1t_l; p4.wl1 = Wr1t_l + (size_t)2048 * 2048;
        p4.of0 = hif; p4.of1 = hjf;
        p4.K = 2048; p4.ldc = 2048; p4.coloff1 = 0;
        gemm_split<false, false, false><<<dim3(8, 32, 2), blk, 0, stream>>>(p4);

        big_mfma<<<dim3(256, 4), dim3(512), 0, stream>>>(hif, hjf, br1, Wr2t_h, br2, out);
    } else {
        // ---------------- fp32 fallback (round-1 structure) ----------------
        u16* Wt = (u16*)d_ws;                               // 4 MB
        float* ws  = (float*)((char*)d_ws + (size_t)Dm * D2 * 2);
        float* gs  = ws;
        float* ge  = gs  + 512 * Dm;
        float* t1  = ge  + 512 * Dm;
        float* cat = t1  + 512 * D2;
        float* ent = cat + 512 * D2;
        float* hi  = ent + 512 * D2;
        float* hj  = hi  + 512 * D2;

        TransJobs J = {};
        J.src[0] = Wr2; J.dh[0] = Wt; J.dl[0] = nullptr;
        J.K[0] = 2048; J.N[0] = 1024; J.tiles[0] = 512;
        transpose_split<<<dim3(512), blk, 0, stream>>>(J);

        gather_rows<<<dim3(512, 2), blk, 0, stream>>>(h, span, gs, ge);
        gemm_f32<true,  true><<<dim3(8, 32), blk, 0, stream>>>(gs, Dm, Ws1, D2, bs1, t1, D2, Dm);
        gemm_f32<true,  true><<<dim3(8, 16), blk, 0, stream>>>(t1, D2, Ws2, Dm, bs2, cat, D2, D2);
        gemm_f32<true,  true><<<dim3(8, 32), blk, 0, stream>>>(ge, Dm, We1, D2, be1, t1, D2, Dm);
        gemm_f32<true,  true><<<dim3(8, 16), blk, 0, stream>>>(t1, D2, We2, Dm, be2, cat + Dm, D2, D2);
        gemm_f32<false, true><<<dim3(8, 32), blk, 0, stream>>>(cat, D2, Wo, D2, bo, ent, D2, D2);
        gemm_f32<false, false><<<dim3(8, 32), blk, 0, stream>>>(ent, D2, Wr1, D2, nullptr, hi, D2, D2);
        gemm_f32<false, false><<<dim3(8, 32), blk, 0, stream>>>(ent, D2, Wr1 + (size_t)D2 * D2, D2, nullptr, hj, D2, D2);
        big_mfma<<<dim3(256, 4), dim3(512), 0, stream>>>(hi, hj, br1, Wt, br2, out);
    }
}

// Round 5
// 490.757 us; speedup vs baseline: 1.3356x; 1.0258x over previous
//
#include <hip/hip_runtime.h>
#include <hip/hip_bf16.h>

// Problem constants: B=8, L=512, N=64, D=1024
constexpr int Lseq = 512;
constexpr int Nsp  = 64;
constexpr int Dm   = 1024;   // D
constexpr int D2   = 2048;   // 2D

typedef __attribute__((ext_vector_type(8))) short short8;
typedef __attribute__((ext_vector_type(4))) float floatx4;
typedef unsigned short u16;
typedef unsigned int   u32;

__device__ __forceinline__ u32 f2bf(float x) {
    u32 u = __float_as_uint(x);
    return (u + 0x7fffu + ((u >> 16) & 1u)) >> 16;   // RNE
}
__device__ __forceinline__ float bf2f(u32 hbits) {
    return __uint_as_float(hbits << 16);
}
__device__ __forceinline__ u32 pk2(float x0, float x1) {
    __hip_bfloat162 bb = __float22bfloat162_rn(make_float2(x0, x1));
    u32 r; __builtin_memcpy(&r, &bb, 4); return r;
}

// XOR swizzle for 64B-row LDS tiles (32 u16 per row): spread 16 same-chunk
// rows over all 8 bank quads.  u16-index form: idx ^= ((row>>1)&3)<<3.
// (big_mfma BK=32 tiles; measured 0 bank conflicts, R2.)
__device__ __forceinline__ int swz_idx(int row, int chunk8) {
    return (row * 32 + chunk8 * 8) ^ (((row >> 1) & 3) << 3);
}

// ---------------------------------------------------------------------------
// Gather h rows at span indices, emitting hi/lo bf16 split. grid (512,2).
// ---------------------------------------------------------------------------
__global__ __launch_bounds__(256)
void gather_split(const float* __restrict__ h, const int* __restrict__ span,
                  u16* __restrict__ g_hi, u16* __restrict__ g_lo)
{
    const int row = blockIdx.x, which = blockIdx.y;
    const int b = row >> 6;
    const int idx = span[row * 2 + which];
    const float4* src = (const float4*)(h + ((size_t)b * Lseq + idx) * Dm);
    float4 v = src[threadIdx.x];
    u32 h01 = pk2(v.x, v.y), h23 = pk2(v.z, v.w);
    u32 l01 = pk2(v.x - bf2f(h01 & 0xffffu), v.y - bf2f(h01 >> 16));
    u32 l23 = pk2(v.z - bf2f(h23 & 0xffffu), v.w - bf2f(h23 >> 16));
    size_t off = ((size_t)which * 512 + row) * Dm + (size_t)threadIdx.x * 4;
    *(uint2*)(g_hi + off) = make_uint2(h01, h23);
    *(uint2*)(g_lo + off) = make_uint2(l01, l23);
}

// Plain fp32 gather (fallback path)
__global__ __launch_bounds__(256)
void gather_rows(const float* __restrict__ h, const int* __restrict__ span,
                 float* __restrict__ gs, float* __restrict__ ge)
{
    const int row = blockIdx.x, which = blockIdx.y;
    const int b = row >> 6;
    const int idx = span[row * 2 + which];
    const float4* src = (const float4*)(h + ((size_t)b * Lseq + idx) * Dm);
    float4* dst = (float4*)((which ? ge : gs) + (size_t)row * Dm);
    dst[threadIdx.x] = src[threadIdx.x];
}

// ---------------------------------------------------------------------------
// Batched weight transpose+split: W[k][n] fp32 -> Wt_hi/lo[n][k] bf16.
// ---------------------------------------------------------------------------
struct TransJobs {
    const float* src[8];
    u16* dh[8];
    u16* dl[8];
    int K[8], N[8], tiles[8];
};

__global__ __launch_bounds__(256)
void transpose_split(TransJobs J)
{
    __shared__ float T[64][65];
    int b = blockIdx.x, j = 0;
    while (b >= J.tiles[j]) { b -= J.tiles[j]; ++j; }
    const float* src = J.src[j];
    const int K = J.K[j], N = J.N[j];
    const int tk = K >> 6;
    const int k0 = (b % tk) * 64, n0 = (b / tk) * 64;
    const int t = threadIdx.x, c = t & 63, r4 = t >> 6;
#pragma unroll
    for (int s = 0; s < 16; ++s) {
        int r = r4 * 16 + s;
        T[r][c] = src[(size_t)(k0 + r) * N + n0 + c];
    }
    __syncthreads();
    u16* dh = J.dh[j];
    u16* dl = J.dl[j];
#pragma unroll
    for (int s = 0; s < 16; ++s) {
        int n = r4 * 16 + s;
        float v = T[c][n];
        u32 hv = f2bf(v);
        dh[(size_t)(n0 + n) * K + k0 + c] = (u16)hv;
        if (dl) dl[(size_t)(n0 + n) * K + k0 + c] = (u16)f2bf(v - bf2f(hv));
    }
}

// ---------------------------------------------------------------------------
// Split-bf16 MFMA GEMM: C = act(A @ W + bias), A as hi/lo bf16 [M][K],
// W pre-transposed+split Wt_hi/lo[n][k]. Tile 64x64, K-step 64. 4 waves;
// wave w owns rows [w*16, w*16+16). 3 MFMAs per tile pair.
// v5: DOUBLE-BUFFERED LDS (2x 4 tiles x 8KB = 64KB). Grids are 1-2
// blocks/CU (grid-limited occupancy), so single-buffer exposed the full
// staging latency per K-step. Schedule: issue next-tile gloads into buf^1,
// MFMA on buf, ONE __syncthreads per iter (vmcnt drain covered by MFMA).
// LDS 128B-row tiles with chunk^(row&7) swizzle both sides.
// ---------------------------------------------------------------------------
struct GemmP {
    const u16 *ah0, *ah1, *al0, *al1;
    const u16 *wh0, *wh1, *wl0, *wl1;
    const float *b0, *b1;
    float *of0, *of1;
    u16 *oh0, *oh1, *ol0, *ol1;
    int K, ldc, coloff1;
};

template<bool RELU, bool BIAS, bool SPLIT_OUT>
__global__ __launch_bounds__(256)
void gemm_split(GemmP P)
{
    // [buf][64*64] per logical tile; 4 tiles, 2 buffers = 64 KB total.
    __shared__ __align__(16) u16 As_h[2 * 64 * 64];
    __shared__ __align__(16) u16 As_l[2 * 64 * 64];
    __shared__ __align__(16) u16 Bs_h[2 * 64 * 64];
    __shared__ __align__(16) u16 Bs_l[2 * 64 * 64];

    const int tid = threadIdx.x, w = tid >> 6, l = tid & 63;
    const int lr = l & 15, lq = l >> 4;
    const int z = blockIdx.z;
    const int m0 = blockIdx.x * 64, n0 = blockIdx.y * 64;
    const int K = P.K;

    const u16* ah = z ? P.ah1 : P.ah0;
    const u16* al = z ? P.al1 : P.al0;
    const u16* wh = z ? P.wh1 : P.wh0;
    const u16* wl = z ? P.wl1 : P.wl0;

    // Each wave stages one 64x64 bf16 tile (8 KB) via 8 global_load_lds.
    const u16* src; u16* ldst;
    if      (w == 0) { src = ah + (size_t)m0 * K; ldst = As_h; }
    else if (w == 1) { src = al + (size_t)m0 * K; ldst = As_l; }
    else if (w == 2) { src = wh + (size_t)n0 * K; ldst = Bs_h; }
    else             { src = wl + (size_t)n0 * K; ldst = Bs_l; }
    // pre-swizzled source chunk: linear LDS write lands swizzled layout
    const int schunk = (l & 7) ^ ((l >> 3) & 7);
    const u16* sl = src + (size_t)(l >> 3) * K + (size_t)schunk * 8;

    // fragment-read swizzle: row&7 == lr&7 for rows x*16+lr
    const int rswz = (lr & 7) << 3;

    floatx4 acc[4];
#pragma unroll
    for (int nt = 0; nt < 4; ++nt) acc[nt] = (floatx4){0.f, 0.f, 0.f, 0.f};

    // ---- prologue: stage k0=0 into buffer 0 ----
#pragma unroll
    for (int i = 0; i < 8; ++i)
        __builtin_amdgcn_global_load_lds(
            (const __attribute__((address_space(1))) u32*)(sl + (size_t)i * 8 * K),
            (__attribute__((address_space(3))) u32*)(ldst + i * 512), 16, 0, 0);
    __syncthreads();

    int cur = 0;
    for (int k0 = 0; k0 < K; k0 += 64) {
        const int nxt = cur ^ 1;
        // ---- issue next-tile loads first (latency hides under MFMA) ----
        if (k0 + 64 < K) {
            u16* ldstN = ldst + nxt * 4096;
#pragma unroll
            for (int i = 0; i < 8; ++i)
                __builtin_amdgcn_global_load_lds(
                    (const __attribute__((address_space(1))) u32*)(sl + (size_t)i * 8 * K + k0 + 64),
                    (__attribute__((address_space(3))) u32*)(ldstN + i * 512), 16, 0, 0);
        }

        // ---- MFMA on current buffer ----
        const int bo = cur * 4096;
#pragma unroll
        for (int kk = 0; kk < 2; ++kk) {
            const int ar = bo + ((((w * 16 + lr) * 64) + kk * 32 + lq * 8) ^ rswz);
            short8 fah = *(const short8*)&As_h[ar];
            short8 fal = *(const short8*)&As_l[ar];
#pragma unroll
            for (int nt = 0; nt < 4; ++nt) {
                const int brd = bo + ((((nt * 16 + lr) * 64) + kk * 32 + lq * 8) ^ rswz);
                short8 fbh = *(const short8*)&Bs_h[brd];
                short8 fbl = *(const short8*)&Bs_l[brd];
                acc[nt] = __builtin_amdgcn_mfma_f32_16x16x32_bf16(fah, fbh, acc[nt], 0, 0, 0);
                acc[nt] = __builtin_amdgcn_mfma_f32_16x16x32_bf16(fal, fbh, acc[nt], 0, 0, 0);
                acc[nt] = __builtin_amdgcn_mfma_f32_16x16x32_bf16(fah, fbl, acc[nt], 0, 0, 0);
            }
        }
        // One barrier per iter: drains the just-issued gloads (covered by
        // the MFMA above) and guards buffer reuse.
        __syncthreads();
        cur = nxt;
    }

    const float* bias = z ? P.b1 : P.b0;
    const int colb = n0 + (z ? P.coloff1 : 0);
    float bv[4];
    if (BIAS) {
#pragma unroll
        for (int nt = 0; nt < 4; ++nt) bv[nt] = bias[n0 + nt * 16 + lr];
    }
#pragma unroll
    for (int nt = 0; nt < 4; ++nt) {
#pragma unroll
        for (int r = 0; r < 4; ++r) {
            float x = acc[nt][r];
            if (BIAS) x += bv[nt];
            if (RELU) x = fmaxf(x, 0.f);
            const int m = m0 + w * 16 + lq * 4 + r;
            const size_t oidx = (size_t)m * P.ldc + colb + nt * 16 + lr;
            if (SPLIT_OUT) {
                u16* oh = z ? P.oh1 : P.oh0;
                u16* ol = z ? P.ol1 : P.ol0;
                u32 hv = f2bf(x);
                oh[oidx] = (u16)hv;
                ol[oidx] = (u16)f2bf(x - bf2f(hv));
            } else {
                float* of = z ? P.of1 : P.of0;
                of[oidx] = x;
            }
        }
    }
}

// ---------------------------------------------------------------------------
// fp32 GEMM fallback (round-1) for small layers if ws is too small.
// ---------------------------------------------------------------------------
template<bool RELU, bool BIAS>
__global__ __launch_bounds__(256)
void gemm_f32(const float* __restrict__ A, int lda,
              const float* __restrict__ W, int ldw,
              const float* __restrict__ bias,
              float* __restrict__ C, int ldc, int K)
{
    __shared__ float As[16][64];
    __shared__ float Ws[16][64];
    const int tid = threadIdx.x;
    const int tx = tid & 15, ty = tid >> 4;
    const int m0 = blockIdx.x * 64, n0 = blockIdx.y * 64;
    const int la_c = tid & 15, la_r = tid >> 4;
    const int lw_n = tid & 63, lw_k = tid >> 6;
    float acc[4][4] = {};
    for (int k0 = 0; k0 < K; k0 += 16) {
#pragma unroll
        for (int s = 0; s < 4; ++s) {
            int m = la_r + 16 * s;
            As[la_c][m] = A[(size_t)(m0 + m) * lda + k0 + la_c];
        }
#pragma unroll
        for (int s = 0; s < 4; ++s) {
            int k = lw_k + 4 * s;
            Ws[k][lw_n] = W[(size_t)(k0 + k) * ldw + n0 + lw_n];
        }
        __syncthreads();
#pragma unroll
        for (int kk = 0; kk < 16; ++kk) {
            float a4[4], w4[4];
            *(float4*)a4 = *(const float4*)&As[kk][ty * 4];
            *(float4*)w4 = *(const float4*)&Ws[kk][tx * 4];
#pragma unroll
            for (int i = 0; i < 4; ++i)
#pragma unroll
                for (int j = 0; j < 4; ++j)
                    acc[i][j] = fmaf(a4[i], w4[j], acc[i][j]);
        }
        __syncthreads();
    }
#pragma unroll
    for (int i = 0; i < 4; ++i) {
        float4 v; float* vp = (float*)&v;
#pragma unroll
        for (int j = 0; j < 4; ++j) {
            float x = acc[i][j];
            if (BIAS) x += bias[n0 + tx * 4 + j];
            if (RELU) x = fmaxf(x, 0.f);
            vp[j] = x;
        }
        *(float4*)&C[(size_t)(m0 + ty * 4 + i) * ldc + n0 + tx * 4] = v;
    }
}

// ---------------------------------------------------------------------------
// Final GEMM via bf16 MFMA; hidden = relu(hi ⊕ hj + br1) built on the fly.
// 512 threads, 8 waves (wm 0..1 × wn 0..3), tile 128(M)x256(N), grid (256,4).
// R2-proven version: K-step 32, [row][32] tiles, XOR swizzle
// idx ^= ((row>>1)&3)<<3 on BOTH sides (A: per-lane ds_write + read;
// B: pre-swizzled global source + read).  B gload_lds before A-build VALU.
// NOTE: BK=64 here spills (reg budget 128 @ launch_bounds(512,4)) — R3
// measured 489 MiB scratch writes, 2x dur. Do not raise BK or add regs
// without watching WRITE_SIZE for the spill signature.
// ---------------------------------------------------------------------------
__global__ __launch_bounds__(512, 4)
void big_mfma(const float* __restrict__ hi, const float* __restrict__ hj,
              const float* __restrict__ br1, const u16* __restrict__ Wt,
              const float* __restrict__ br2, float* __restrict__ out)
{
    __shared__ float hiP[2][D2];                     // 16 KB
    __shared__ __align__(16) u16 Asb[128 * 32];      // swizzled [128][32], 8 KB
    __shared__ __align__(16) u16 Bsb[256 * 32];      // swizzled [256][32], 16 KB

    const int tid = threadIdx.x;
    const int p = blockIdx.x, n0 = blockIdx.y * 256;
    const int b = p >> 5, bi0 = p * 2;

    // A-build assignment: one (row, k-chunk) per thread.
    const int rowA = tid >> 2, kq = tid & 3;
    const int selA = rowA >> 6, jA = rowA & 63;
    const float* hjrow = hj + ((size_t)b * 64 + jA) * D2 + kq * 8;
    u16* astore = Asb + swz_idx(rowA, kq);
    const float* hip = hiP[selA] + kq * 8;

    // Prefetch hj chunk for k0=0 (in flight during hiP staging).
    float4 pf0 = *(const float4*)(hjrow);
    float4 pf1 = *(const float4*)(hjrow + 4);

    // hiP = hi(+pair) + br1  (1024 float4 over 512 threads)
    {
        const float4* h0 = (const float4*)(hi + (size_t)bi0 * D2);
        const float4* h1 = (const float4*)(hi + (size_t)(bi0 + 1) * D2);
        const float4* br = (const float4*)br1;
        float4* d0 = (float4*)hiP[0];
        float4* d1 = (float4*)hiP[1];
        const int v = tid;   // 512 threads, 512 float4 per row
        float4 bb = br[v];
        float4 a = h0[v];
        a.x += bb.x; a.y += bb.y; a.z += bb.z; a.w += bb.w;
        d0[v] = a;
        float4 c = h1[v];
        c.x += bb.x; c.y += bb.y; c.z += bb.z; c.w += bb.w;
        d1[v] = c;
    }

    const int w = tid >> 6, l = tid & 63;
    const int wm = w & 1, wn = w >> 1;
    const int lr = l & 15, lq = l >> 4;
    const int rswz = ((lr >> 1) & 3) << 3;

    // B source: pre-swizzled chunk so linear gload write == swizzled layout.
    const int schunk = (l & 3) ^ ((l >> 3) & 3);

    floatx4 acc[4][4];
#pragma unroll
    for (int mt = 0; mt < 4; ++mt)
#pragma unroll
        for (int nt = 0; nt < 4; ++nt)
            acc[mt][nt] = (floatx4){0.f, 0.f, 0.f, 0.f};

    for (int k0 = 0; k0 < D2; k0 += 32) {
        __syncthreads();

        // ---- B tile: async bf16 stage first (hides under A-build) ----
#pragma unroll
        for (int c = 0; c < 2; ++c) {
            const u16* g = Wt + (size_t)(n0 + w * 32 + c * 16 + (l >> 2)) * D2
                              + k0 + schunk * 8;
            u16* lp = Bsb + (w * 32 + c * 16) * 32;
            __builtin_amdgcn_global_load_lds(
                (const __attribute__((address_space(1))) u32*)g,
                (__attribute__((address_space(3))) u32*)lp, 16, 0, 0);
        }

        // ---- A tile: relu(hi' + hj) -> bf16, swizzled store ----
        {
            float4 h0 = *(const float4*)(hip + k0);
            float4 h1 = *(const float4*)(hip + k0 + 4);
            u32 u0 = pk2(fmaxf(pf0.x + h0.x, 0.f), fmaxf(pf0.y + h0.y, 0.f));
            u32 u1 = pk2(fmaxf(pf0.z + h0.z, 0.f), fmaxf(pf0.w + h0.w, 0.f));
            u32 u2 = pk2(fmaxf(pf1.x + h1.x, 0.f), fmaxf(pf1.y + h1.y, 0.f));
            u32 u3 = pk2(fmaxf(pf1.z + h1.z, 0.f), fmaxf(pf1.w + h1.w, 0.f));
            *(uint4*)astore = make_uint4(u0, u1, u2, u3);
        }

        __syncthreads();

        // ---- prefetch next-k hj (flies during MFMA cluster) ----
        if (k0 + 32 < D2) {
            pf0 = *(const float4*)(hjrow + k0 + 32);
            pf1 = *(const float4*)(hjrow + k0 + 36);
        }

        // ---- fragments + MFMA ----
        short8 af[4], bfr[4];
#pragma unroll
        for (int mt = 0; mt < 4; ++mt)
            af[mt] = *(const short8*)&Asb[(((wm * 64 + mt * 16 + lr) * 32) + lq * 8) ^ rswz];
#pragma unroll
        for (int nt = 0; nt < 4; ++nt)
            bfr[nt] = *(const short8*)&Bsb[(((wn * 64 + nt * 16 + lr) * 32) + lq * 8) ^ rswz];
        __builtin_amdgcn_s_setprio(1);
#pragma unroll
        for (int mt = 0; mt < 4; ++mt)
#pragma unroll
            for (int nt = 0; nt < 4; ++nt)
                acc[mt][nt] = __builtin_amdgcn_mfma_f32_16x16x32_bf16(
                    af[mt], bfr[nt], acc[mt][nt], 0, 0, 0);
        __builtin_amdgcn_s_setprio(0);
    }

    // ---- epilogue ----
    float bias[4];
#pragma unroll
    for (int nt = 0; nt < 4; ++nt)
        bias[nt] = br2[n0 + wn * 64 + nt * 16 + lr];

#pragma unroll
    for (int mt = 0; mt < 4; ++mt) {
        const int mbase = wm * 64 + mt * 16 + lq * 4;
#pragma unroll
        for (int r = 0; r < 4; ++r) {
            const int mm = mbase + r;
            const int sel = mm >> 6, j = mm & 63;
            float* orow = out + (((size_t)(bi0 + sel) * 64 + j) * Dm) + n0 + wn * 64;
#pragma unroll
            for (int nt = 0; nt < 4; ++nt)
                orow[nt * 16 + lr] = acc[mt][nt][r] + bias[nt];
        }
    }
}

// ---------------------------------------------------------------------------
extern "C" void kernel_launch(void* const* d_in, const int* in_sizes, int n_in,
                              void* d_out, int out_size, void* d_ws, size_t ws_size,
                              hipStream_t stream) {
    const float* h    = (const float*)d_in[0];
    const int*   span = (const int*)  d_in[1];
    const float* Ws1  = (const float*)d_in[2];
    const float* bs1  = (const float*)d_in[3];
    const float* Ws2  = (const float*)d_in[4];
    const float* bs2  = (const float*)d_in[5];
    const float* We1  = (const float*)d_in[6];
    const float* be1  = (const float*)d_in[7];
    const float* We2  = (const float*)d_in[8];
    const float* be2  = (const float*)d_in[9];
    const float* Wo   = (const float*)d_in[10];
    const float* bo   = (const float*)d_in[11];
    const float* Wr1  = (const float*)d_in[12];
    const float* br1  = (const float*)d_in[13];
    const float* Wr2  = (const float*)d_in[14];
    const float* br2  = (const float*)d_in[15];
    float* out = (float*)d_out;

    dim3 blk(256);
    const size_t REQUIRED = (size_t)120 << 20;

    if (ws_size >= REQUIRED) {
        // ---------------- split-bf16 MFMA path ----------------
        char* W = (char*)d_ws;
        size_t off = 0;
        auto alloc = [&](size_t bytes) { char* q = W + off; off += bytes; return q; };

        u16* W1t_h = (u16*)alloc((size_t)2 * 2048 * 1024 * 2);
        u16* W1t_l = (u16*)alloc((size_t)2 * 2048 * 1024 * 2);
        u16* W2t_h = (u16*)alloc((size_t)2 * 1024 * 2048 * 2);
        u16* W2t_l = (u16*)alloc((size_t)2 * 1024 * 2048 * 2);
        u16* Wot_h = (u16*)alloc((size_t)2048 * 2048 * 2);
        u16* Wot_l = (u16*)alloc((size_t)2048 * 2048 * 2);
        u16* Wr1t_h = (u16*)alloc((size_t)2 * 2048 * 2048 * 2);
        u16* Wr1t_l = (u16*)alloc((size_t)2 * 2048 * 2048 * 2);
        u16* Wr2t_h = (u16*)alloc((size_t)1024 * 2048 * 2);
        u16* gs_h  = (u16*)alloc((size_t)2 * 512 * 1024 * 2);
        u16* gs_l  = (u16*)alloc((size_t)2 * 512 * 1024 * 2);
        u16* t1_h  = (u16*)alloc((size_t)2 * 512 * 2048 * 2);
        u16* t1_l  = (u16*)alloc((size_t)2 * 512 * 2048 * 2);
        u16* cat_h = (u16*)alloc((size_t)512 * 2048 * 2);
        u16* cat_l = (u16*)alloc((size_t)512 * 2048 * 2);
        u16* ent_h = (u16*)alloc((size_t)512 * 2048 * 2);
        u16* ent_l = (u16*)alloc((size_t)512 * 2048 * 2);
        float* hif = (float*)alloc((size_t)512 * 2048 * 4);
        float* hjf = (float*)alloc((size_t)512 * 2048 * 4);

        TransJobs J;
        J.src[0] = Ws1;  J.dh[0] = W1t_h;                J.dl[0] = W1t_l;                J.K[0] = 1024; J.N[0] = 2048; J.tiles[0] = 512;
        J.src[1] = We1;  J.dh[1] = W1t_h + 2048 * 1024;  J.dl[1] = W1t_l + 2048 * 1024;  J.K[1] = 1024; J.N[1] = 2048; J.tiles[1] = 512;
        J.src[2] = Ws2;  J.dh[2] = W2t_h;                J.dl[2] = W2t_l;                J.K[2] = 2048; J.N[2] = 1024; J.tiles[2] = 512;
        J.src[3] = We2;  J.dh[3] = W2t_h + 1024 * 2048;  J.dl[3] = W2t_l + 1024 * 2048;  J.K[3] = 2048; J.N[3] = 1024; J.tiles[3] = 512;
        J.src[4] = Wo;   J.dh[4] = Wot_h;                J.dl[4] = Wot_l;                J.K[4] = 2048; J.N[4] = 2048; J.tiles[4] = 1024;
        J.src[5] = Wr1;  J.dh[5] = Wr1t_h;               J.dl[5] = Wr1t_l;               J.K[5] = 2048; J.N[5] = 2048; J.tiles[5] = 1024;
        J.src[6] = Wr1 + (size_t)2048 * 2048;
                         J.dh[6] = Wr1t_h + (size_t)2048 * 2048; J.dl[6] = Wr1t_l + (size_t)2048 * 2048;
                                                                          J.K[6] = 2048; J.N[6] = 2048; J.tiles[6] = 1024;
        J.src[7] = Wr2;  J.dh[7] = Wr2t_h;               J.dl[7] = nullptr;              J.K[7] = 2048; J.N[7] = 1024; J.tiles[7] = 512;
        transpose_split<<<dim3(5632), blk, 0, stream>>>(J);

        gather_split<<<dim3(512, 2), blk, 0, stream>>>(h, span, gs_h, gs_l);

        GemmP p1 = {};
        p1.ah0 = gs_h; p1.ah1 = gs_h + 512 * 1024;
        p1.al0 = gs_l; p1.al1 = gs_l + 512 * 1024;
        p1.wh0 = W1t_h; p1.wh1 = W1t_h + 2048 * 1024;
        p1.wl0 = W1t_l; p1.wl1 = W1t_l + 2048 * 1024;
        p1.b0 = bs1; p1.b1 = be1;
        p1.oh0 = t1_h; p1.oh1 = t1_h + 512 * 2048;
        p1.ol0 = t1_l; p1.ol1 = t1_l + 512 * 2048;
        p1.K = 1024; p1.ldc = 2048; p1.coloff1 = 0;
        gemm_split<true, true, true><<<dim3(8, 32, 2), blk, 0, stream>>>(p1);

        GemmP p2 = {};
        p2.ah0 = t1_h; p2.ah1 = t1_h + 512 * 2048;
        p2.al0 = t1_l; p2.al1 = t1_l + 512 * 2048;
        p2.wh0 = W2t_h; p2.wh1 = W2t_h + 1024 * 2048;
        p2.wl0 = W2t_l; p2.wl1 = W2t_l + 1024 * 2048;
        p2.b0 = bs2; p2.b1 = be2;
        p2.oh0 = cat_h; p2.oh1 = cat_h;
        p2.ol0 = cat_l; p2.ol1 = cat_l;
        p2.K = 2048; p2.ldc = 2048; p2.coloff1 = 1024;
        gemm_split<true, true, true><<<dim3(8, 16, 2), blk, 0, stream>>>(p2);

        GemmP p3 = {};
        p3.ah0 = cat_h; p3.al0 = cat_l;
        p3.wh0 = Wot_h; p3.wl0 = Wot_l;
        p3.b0 = bo;
        p3.oh0 = ent_h; p3.ol0 = ent_l;
        p3.K = 2048; p3.ldc = 2048; p3.coloff1 = 0;
        gemm_split<false, true, true><<<dim3(8, 32, 1), blk, 0, stream>>>(p3);

        GemmP p4 = {};
        p4.ah0 = ent_h; p4.ah1 = ent_h;
        p4.al0 = ent_l; p4.al1 = ent_l;
        p4.wh0 = Wr1t_h; p4.wh1 = Wr1t_h + (size_t)2048 * 2048;
        p4.wl0 = Wr1t_l; p4.wl1 = Wr1t_l + (size_t)2048 * 2048;
        p4.of0 = hif; p4.of1 = hjf;
        p4.K = 2048; p4.ldc = 2048; p4.coloff1 = 0;
        gemm_split<false, false, false><<<dim3(8, 32, 2), blk, 0, stream>>>(p4);

        big_mfma<<<dim3(256, 4), dim3(512), 0, stream>>>(hif, hjf, br1, Wr2t_h, br2, out);
    } else {
        // ---------------- fp32 fallback (round-1 structure) ----------------
        u16* Wt = (u16*)d_ws;                               // 4 MB
        float* ws  = (float*)((char*)d_ws + (size_t)Dm * D2 * 2);
        float* gs  = ws;
        float* ge  = gs  + 512 * Dm;
        float* t1  = ge  + 512 * Dm;
        float* cat = t1  + 512 * D2;
        float* ent = cat + 512 * D2;
        float* hi  = ent + 512 * D2;
        float* hj  = hi  + 512 * D2;

        TransJobs J = {};
        J.src[0] = Wr2; J.dh[0] = Wt; J.dl[0] = nullptr;
        J.K[0] = 2048; J.N[0] = 1024; J.tiles[0] = 512;
        transpose_split<<<dim3(512), blk, 0, stream>>>(J);

        gather_rows<<<dim3(512, 2), blk, 0, stream>>>(h, span, gs, ge);
        gemm_f32<true,  true><<<dim3(8, 32), blk, 0, stream>>>(gs, Dm, Ws1, D2, bs1, t1, D2, Dm);
        gemm_f32<true,  true><<<dim3(8, 16), blk, 0, stream>>>(t1, D2, Ws2, Dm, bs2, cat, D2, D2);
        gemm_f32<true,  true><<<dim3(8, 32), blk, 0, stream>>>(ge, Dm, We1, D2, be1, t1, D2, Dm);
        gemm_f32<true,  true><<<dim3(8, 16), blk, 0, stream>>>(t1, D2, We2, Dm, be2, cat + Dm, D2, D2);
        gemm_f32<false, true><<<dim3(8, 32), blk, 0, stream>>>(cat, D2, Wo, D2, bo, ent, D2, D2);
        gemm_f32<false, false><<<dim3(8, 32), blk, 0, stream>>>(ent, D2, Wr1, D2, nullptr, hi, D2, D2);
        gemm_f32<false, false><<<dim3(8, 32), blk, 0, stream>>>(ent, D2, Wr1 + (size_t)D2 * D2, D2, nullptr, hj, D2, D2);
        big_mfma<<<dim3(256, 4), dim3(512), 0, stream>>>(hi, hj, br1, Wt, br2, out);
    }
}

// Round 6
// 477.100 us; speedup vs baseline: 1.3739x; 1.0286x over previous
//
#include <hip/hip_runtime.h>
#include <hip/hip_bf16.h>

// Problem constants: B=8, L=512, N=64, D=1024
constexpr int Lseq = 512;
constexpr int Nsp  = 64;
constexpr int Dm   = 1024;   // D
constexpr int D2   = 2048;   // 2D

typedef __attribute__((ext_vector_type(8))) short short8;
typedef __attribute__((ext_vector_type(4))) float floatx4;
typedef unsigned short u16;
typedef unsigned int   u32;

__device__ __forceinline__ u32 f2bf(float x) {
    u32 u = __float_as_uint(x);
    return (u + 0x7fffu + ((u >> 16) & 1u)) >> 16;   // RNE
}
__device__ __forceinline__ float bf2f(u32 hbits) {
    return __uint_as_float(hbits << 16);
}
__device__ __forceinline__ u32 pk2(float x0, float x1) {
    __hip_bfloat162 bb = __float22bfloat162_rn(make_float2(x0, x1));
    u32 r; __builtin_memcpy(&r, &bb, 4); return r;
}

// XOR swizzle for 64B-row LDS tiles (32 u16 per row): spread 16 same-chunk
// rows over all 8 bank quads.  u16-index form: idx ^= ((row>>1)&3)<<3.
// (big_mfma BK=32 tiles; measured 0 bank conflicts, R2.)
__device__ __forceinline__ int swz_idx(int row, int chunk8) {
    return (row * 32 + chunk8 * 8) ^ (((row >> 1) & 3) << 3);
}

// ---------------------------------------------------------------------------
// Gather h rows at span indices, emitting hi/lo bf16 split. grid (512,2).
// ---------------------------------------------------------------------------
__global__ __launch_bounds__(256)
void gather_split(const float* __restrict__ h, const int* __restrict__ span,
                  u16* __restrict__ g_hi, u16* __restrict__ g_lo)
{
    const int row = blockIdx.x, which = blockIdx.y;
    const int b = row >> 6;
    const int idx = span[row * 2 + which];
    const float4* src = (const float4*)(h + ((size_t)b * Lseq + idx) * Dm);
    float4 v = src[threadIdx.x];
    u32 h01 = pk2(v.x, v.y), h23 = pk2(v.z, v.w);
    u32 l01 = pk2(v.x - bf2f(h01 & 0xffffu), v.y - bf2f(h01 >> 16));
    u32 l23 = pk2(v.z - bf2f(h23 & 0xffffu), v.w - bf2f(h23 >> 16));
    size_t off = ((size_t)which * 512 + row) * Dm + (size_t)threadIdx.x * 4;
    *(uint2*)(g_hi + off) = make_uint2(h01, h23);
    *(uint2*)(g_lo + off) = make_uint2(l01, l23);
}

// Plain fp32 gather (fallback path)
__global__ __launch_bounds__(256)
void gather_rows(const float* __restrict__ h, const int* __restrict__ span,
                 float* __restrict__ gs, float* __restrict__ ge)
{
    const int row = blockIdx.x, which = blockIdx.y;
    const int b = row >> 6;
    const int idx = span[row * 2 + which];
    const float4* src = (const float4*)(h + ((size_t)b * Lseq + idx) * Dm);
    float4* dst = (float4*)((which ? ge : gs) + (size_t)row * Dm);
    dst[threadIdx.x] = src[threadIdx.x];
}

// ---------------------------------------------------------------------------
// Batched weight transpose+split: W[k][n] fp32 -> Wt_hi/lo[n][k] bf16.
// ---------------------------------------------------------------------------
struct TransJobs {
    const float* src[8];
    u16* dh[8];
    u16* dl[8];
    int K[8], N[8], tiles[8];
};

__global__ __launch_bounds__(256)
void transpose_split(TransJobs J)
{
    __shared__ float T[64][65];
    int b = blockIdx.x, j = 0;
    while (b >= J.tiles[j]) { b -= J.tiles[j]; ++j; }
    const float* src = J.src[j];
    const int K = J.K[j], N = J.N[j];
    const int tk = K >> 6;
    const int k0 = (b % tk) * 64, n0 = (b / tk) * 64;
    const int t = threadIdx.x, c = t & 63, r4 = t >> 6;
#pragma unroll
    for (int s = 0; s < 16; ++s) {
        int r = r4 * 16 + s;
        T[r][c] = src[(size_t)(k0 + r) * N + n0 + c];
    }
    __syncthreads();
    u16* dh = J.dh[j];
    u16* dl = J.dl[j];
#pragma unroll
    for (int s = 0; s < 16; ++s) {
        int n = r4 * 16 + s;
        float v = T[c][n];
        u32 hv = f2bf(v);
        dh[(size_t)(n0 + n) * K + k0 + c] = (u16)hv;
        if (dl) dl[(size_t)(n0 + n) * K + k0 + c] = (u16)f2bf(v - bf2f(hv));
    }
}

// ---------------------------------------------------------------------------
// Split-bf16 MFMA GEMM: C = act(A @ W + bias), A as hi/lo bf16 [M][K],
// W pre-transposed+split Wt_hi/lo[n][k]. Tile 64x64, K-step 64, 4 waves,
// double-buffered LDS (R5).
// v6: XCD-AWARE PANEL SWIZZLE. The mid-GEMMs are staging-BW bound: all 8
// m-blocks of an (n,z) panel read the same 512KB B-panel, but linear grids
// round-robin them across 8 XCDs (zero L2 reuse -> ~1.6GB LLC streaming).
// Remap: hw block h -> xcd=h&7, j=h>>3, m=j&7, panel=(j>>3)*8+xcd, so a
// panel's 8 m-blocks share one XCD's L2 (requires m_tiles==8, panels%8==0,
// true for all four calls). Bijective: perf-only, no correctness risk.
// ---------------------------------------------------------------------------
struct GemmP {
    const u16 *ah0, *ah1, *al0, *al1;
    const u16 *wh0, *wh1, *wl0, *wl1;
    const float *b0, *b1;
    float *of0, *of1;
    u16 *oh0, *oh1, *ol0, *ol1;
    int K, ldc, coloff1, NT;
};

template<bool RELU, bool BIAS, bool SPLIT_OUT>
__global__ __launch_bounds__(256)
void gemm_split(GemmP P)
{
    // [buf][64*64] per logical tile; 4 tiles, 2 buffers = 64 KB total.
    __shared__ __align__(16) u16 As_h[2 * 64 * 64];
    __shared__ __align__(16) u16 As_l[2 * 64 * 64];
    __shared__ __align__(16) u16 Bs_h[2 * 64 * 64];
    __shared__ __align__(16) u16 Bs_l[2 * 64 * 64];

    const int tid = threadIdx.x, w = tid >> 6, l = tid & 63;
    const int lr = l & 15, lq = l >> 4;

    // XCD-aware decode (see header comment)
    const int hb = blockIdx.x;
    const int xcd = hb & 7;
    const int j = hb >> 3;
    const int mb = j & 7;               // 8 m-tiles in all calls
    const int panel = (j >> 3) * 8 + xcd;
    const int nb = panel % P.NT;
    const int z  = panel / P.NT;

    const int m0 = mb * 64, n0 = nb * 64;
    const int K = P.K;

    const u16* ah = z ? P.ah1 : P.ah0;
    const u16* al = z ? P.al1 : P.al0;
    const u16* wh = z ? P.wh1 : P.wh0;
    const u16* wl = z ? P.wl1 : P.wl0;

    // Each wave stages one 64x64 bf16 tile (8 KB) via 8 global_load_lds.
    const u16* src; u16* ldst;
    if      (w == 0) { src = ah + (size_t)m0 * K; ldst = As_h; }
    else if (w == 1) { src = al + (size_t)m0 * K; ldst = As_l; }
    else if (w == 2) { src = wh + (size_t)n0 * K; ldst = Bs_h; }
    else             { src = wl + (size_t)n0 * K; ldst = Bs_l; }
    // pre-swizzled source chunk: linear LDS write lands swizzled layout
    const int schunk = (l & 7) ^ ((l >> 3) & 7);
    const u16* sl = src + (size_t)(l >> 3) * K + (size_t)schunk * 8;

    // fragment-read swizzle: row&7 == lr&7 for rows x*16+lr
    const int rswz = (lr & 7) << 3;

    floatx4 acc[4];
#pragma unroll
    for (int nt = 0; nt < 4; ++nt) acc[nt] = (floatx4){0.f, 0.f, 0.f, 0.f};

    // ---- prologue: stage k0=0 into buffer 0 ----
#pragma unroll
    for (int i = 0; i < 8; ++i)
        __builtin_amdgcn_global_load_lds(
            (const __attribute__((address_space(1))) u32*)(sl + (size_t)i * 8 * K),
            (__attribute__((address_space(3))) u32*)(ldst + i * 512), 16, 0, 0);
    __syncthreads();

    int cur = 0;
    for (int k0 = 0; k0 < K; k0 += 64) {
        const int nxt = cur ^ 1;
        // ---- issue next-tile loads first (latency hides under MFMA) ----
        if (k0 + 64 < K) {
            u16* ldstN = ldst + nxt * 4096;
#pragma unroll
            for (int i = 0; i < 8; ++i)
                __builtin_amdgcn_global_load_lds(
                    (const __attribute__((address_space(1))) u32*)(sl + (size_t)i * 8 * K + k0 + 64),
                    (__attribute__((address_space(3))) u32*)(ldstN + i * 512), 16, 0, 0);
        }

        // ---- MFMA on current buffer ----
        const int bo = cur * 4096;
#pragma unroll
        for (int kk = 0; kk < 2; ++kk) {
            const int ar = bo + ((((w * 16 + lr) * 64) + kk * 32 + lq * 8) ^ rswz);
            short8 fah = *(const short8*)&As_h[ar];
            short8 fal = *(const short8*)&As_l[ar];
#pragma unroll
            for (int nt = 0; nt < 4; ++nt) {
                const int brd = bo + ((((nt * 16 + lr) * 64) + kk * 32 + lq * 8) ^ rswz);
                short8 fbh = *(const short8*)&Bs_h[brd];
                short8 fbl = *(const short8*)&Bs_l[brd];
                acc[nt] = __builtin_amdgcn_mfma_f32_16x16x32_bf16(fah, fbh, acc[nt], 0, 0, 0);
                acc[nt] = __builtin_amdgcn_mfma_f32_16x16x32_bf16(fal, fbh, acc[nt], 0, 0, 0);
                acc[nt] = __builtin_amdgcn_mfma_f32_16x16x32_bf16(fah, fbl, acc[nt], 0, 0, 0);
            }
        }
        // One barrier per iter: drains the just-issued gloads (covered by
        // the MFMA above) and guards buffer reuse.
        __syncthreads();
        cur = nxt;
    }

    const float* bias = z ? P.b1 : P.b0;
    const int colb = n0 + (z ? P.coloff1 : 0);
    float bv[4];
    if (BIAS) {
#pragma unroll
        for (int nt = 0; nt < 4; ++nt) bv[nt] = bias[n0 + nt * 16 + lr];
    }
#pragma unroll
    for (int nt = 0; nt < 4; ++nt) {
#pragma unroll
        for (int r = 0; r < 4; ++r) {
            float x = acc[nt][r];
            if (BIAS) x += bv[nt];
            if (RELU) x = fmaxf(x, 0.f);
            const int m = m0 + w * 16 + lq * 4 + r;
            const size_t oidx = (size_t)m * P.ldc + colb + nt * 16 + lr;
            if (SPLIT_OUT) {
                u16* oh = z ? P.oh1 : P.oh0;
                u16* ol = z ? P.ol1 : P.ol0;
                u32 hv = f2bf(x);
                oh[oidx] = (u16)hv;
                ol[oidx] = (u16)f2bf(x - bf2f(hv));
            } else {
                float* of = z ? P.of1 : P.of0;
                of[oidx] = x;
            }
        }
    }
}

// ---------------------------------------------------------------------------
// fp32 GEMM fallback (round-1) for small layers if ws is too small.
// ---------------------------------------------------------------------------
template<bool RELU, bool BIAS>
__global__ __launch_bounds__(256)
void gemm_f32(const float* __restrict__ A, int lda,
              const float* __restrict__ W, int ldw,
              const float* __restrict__ bias,
              float* __restrict__ C, int ldc, int K)
{
    __shared__ float As[16][64];
    __shared__ float Ws[16][64];
    const int tid = threadIdx.x;
    const int tx = tid & 15, ty = tid >> 4;
    const int m0 = blockIdx.x * 64, n0 = blockIdx.y * 64;
    const int la_c = tid & 15, la_r = tid >> 4;
    const int lw_n = tid & 63, lw_k = tid >> 6;
    float acc[4][4] = {};
    for (int k0 = 0; k0 < K; k0 += 16) {
#pragma unroll
        for (int s = 0; s < 4; ++s) {
            int m = la_r + 16 * s;
            As[la_c][m] = A[(size_t)(m0 + m) * lda + k0 + la_c];
        }
#pragma unroll
        for (int s = 0; s < 4; ++s) {
            int k = lw_k + 4 * s;
            Ws[k][lw_n] = W[(size_t)(k0 + k) * ldw + n0 + lw_n];
        }
        __syncthreads();
#pragma unroll
        for (int kk = 0; kk < 16; ++kk) {
            float a4[4], w4[4];
            *(float4*)a4 = *(const float4*)&As[kk][ty * 4];
            *(float4*)w4 = *(const float4*)&Ws[kk][tx * 4];
#pragma unroll
            for (int i = 0; i < 4; ++i)
#pragma unroll
                for (int j = 0; j < 4; ++j)
                    acc[i][j] = fmaf(a4[i], w4[j], acc[i][j]);
        }
        __syncthreads();
    }
#pragma unroll
    for (int i = 0; i < 4; ++i) {
        float4 v; float* vp = (float*)&v;
#pragma unroll
        for (int j = 0; j < 4; ++j) {
            float x = acc[i][j];
            if (BIAS) x += bias[n0 + tx * 4 + j];
            if (RELU) x = fmaxf(x, 0.f);
            vp[j] = x;
        }
        *(float4*)&C[(size_t)(m0 + ty * 4 + i) * ldc + n0 + tx * 4] = v;
    }
}

// ---------------------------------------------------------------------------
// Final GEMM via bf16 MFMA; hidden = relu(hi ⊕ hj + br1) built on the fly.
// 512 threads, 8 waves (wm 0..1 × wn 0..3), tile 128(M)x256(N), grid (256,4).
// R2-proven version: K-step 32, [row][32] tiles, XOR swizzle
// idx ^= ((row>>1)&3)<<3 on BOTH sides (A: per-lane ds_write + read;
// B: pre-swizzled global source + read).  B gload_lds before A-build VALU.
// NOTE: BK=64 here spills (reg budget 128 @ launch_bounds(512,4)) — R3
// measured 489 MiB scratch writes, 2x dur. Do not raise BK or add regs
// without watching WRITE_SIZE for the spill signature.
// ---------------------------------------------------------------------------
__global__ __launch_bounds__(512, 4)
void big_mfma(const float* __restrict__ hi, const float* __restrict__ hj,
              const float* __restrict__ br1, const u16* __restrict__ Wt,
              const float* __restrict__ br2, float* __restrict__ out)
{
    __shared__ float hiP[2][D2];                     // 16 KB
    __shared__ __align__(16) u16 Asb[128 * 32];      // swizzled [128][32], 8 KB
    __shared__ __align__(16) u16 Bsb[256 * 32];      // swizzled [256][32], 16 KB

    const int tid = threadIdx.x;
    const int p = blockIdx.x, n0 = blockIdx.y * 256;
    const int b = p >> 5, bi0 = p * 2;

    // A-build assignment: one (row, k-chunk) per thread.
    const int rowA = tid >> 2, kq = tid & 3;
    const int selA = rowA >> 6, jA = rowA & 63;
    const float* hjrow = hj + ((size_t)b * 64 + jA) * D2 + kq * 8;
    u16* astore = Asb + swz_idx(rowA, kq);
    const float* hip = hiP[selA] + kq * 8;

    // Prefetch hj chunk for k0=0 (in flight during hiP staging).
    float4 pf0 = *(const float4*)(hjrow);
    float4 pf1 = *(const float4*)(hjrow + 4);

    // hiP = hi(+pair) + br1  (1024 float4 over 512 threads)
    {
        const float4* h0 = (const float4*)(hi + (size_t)bi0 * D2);
        const float4* h1 = (const float4*)(hi + (size_t)(bi0 + 1) * D2);
        const float4* br = (const float4*)br1;
        float4* d0 = (float4*)hiP[0];
        float4* d1 = (float4*)hiP[1];
        const int v = tid;   // 512 threads, 512 float4 per row
        float4 bb = br[v];
        float4 a = h0[v];
        a.x += bb.x; a.y += bb.y; a.z += bb.z; a.w += bb.w;
        d0[v] = a;
        float4 c = h1[v];
        c.x += bb.x; c.y += bb.y; c.z += bb.z; c.w += bb.w;
        d1[v] = c;
    }

    const int w = tid >> 6, l = tid & 63;
    const int wm = w & 1, wn = w >> 1;
    const int lr = l & 15, lq = l >> 4;
    const int rswz = ((lr >> 1) & 3) << 3;

    // B source: pre-swizzled chunk so linear gload write == swizzled layout.
    const int schunk = (l & 3) ^ ((l >> 3) & 3);

    floatx4 acc[4][4];
#pragma unroll
    for (int mt = 0; mt < 4; ++mt)
#pragma unroll
        for (int nt = 0; nt < 4; ++nt)
            acc[mt][nt] = (floatx4){0.f, 0.f, 0.f, 0.f};

    for (int k0 = 0; k0 < D2; k0 += 32) {
        __syncthreads();

        // ---- B tile: async bf16 stage first (hides under A-build) ----
#pragma unroll
        for (int c = 0; c < 2; ++c) {
            const u16* g = Wt + (size_t)(n0 + w * 32 + c * 16 + (l >> 2)) * D2
                              + k0 + schunk * 8;
            u16* lp = Bsb + (w * 32 + c * 16) * 32;
            __builtin_amdgcn_global_load_lds(
                (const __attribute__((address_space(1))) u32*)g,
                (__attribute__((address_space(3))) u32*)lp, 16, 0, 0);
        }

        // ---- A tile: relu(hi' + hj) -> bf16, swizzled store ----
        {
            float4 h0 = *(const float4*)(hip + k0);
            float4 h1 = *(const float4*)(hip + k0 + 4);
            u32 u0 = pk2(fmaxf(pf0.x + h0.x, 0.f), fmaxf(pf0.y + h0.y, 0.f));
            u32 u1 = pk2(fmaxf(pf0.z + h0.z, 0.f), fmaxf(pf0.w + h0.w, 0.f));
            u32 u2 = pk2(fmaxf(pf1.x + h1.x, 0.f), fmaxf(pf1.y + h1.y, 0.f));
            u32 u3 = pk2(fmaxf(pf1.z + h1.z, 0.f), fmaxf(pf1.w + h1.w, 0.f));
            *(uint4*)astore = make_uint4(u0, u1, u2, u3);
        }

        __syncthreads();

        // ---- prefetch next-k hj (flies during MFMA cluster) ----
        if (k0 + 32 < D2) {
            pf0 = *(const float4*)(hjrow + k0 + 32);
            pf1 = *(const float4*)(hjrow + k0 + 36);
        }

        // ---- fragments + MFMA ----
        short8 af[4], bfr[4];
#pragma unroll
        for (int mt = 0; mt < 4; ++mt)
            af[mt] = *(const short8*)&Asb[(((wm * 64 + mt * 16 + lr) * 32) + lq * 8) ^ rswz];
#pragma unroll
        for (int nt = 0; nt < 4; ++nt)
            bfr[nt] = *(const short8*)&Bsb[(((wn * 64 + nt * 16 + lr) * 32) + lq * 8) ^ rswz];
        __builtin_amdgcn_s_setprio(1);
#pragma unroll
        for (int mt = 0; mt < 4; ++mt)
#pragma unroll
            for (int nt = 0; nt < 4; ++nt)
                acc[mt][nt] = __builtin_amdgcn_mfma_f32_16x16x32_bf16(
                    af[mt], bfr[nt], acc[mt][nt], 0, 0, 0);
        __builtin_amdgcn_s_setprio(0);
    }

    // ---- epilogue ----
    float bias[4];
#pragma unroll
    for (int nt = 0; nt < 4; ++nt)
        bias[nt] = br2[n0 + wn * 64 + nt * 16 + lr];

#pragma unroll
    for (int mt = 0; mt < 4; ++mt) {
        const int mbase = wm * 64 + mt * 16 + lq * 4;
#pragma unroll
        for (int r = 0; r < 4; ++r) {
            const int mm = mbase + r;
            const int sel = mm >> 6, j = mm & 63;
            float* orow = out + (((size_t)(bi0 + sel) * 64 + j) * Dm) + n0 + wn * 64;
#pragma unroll
            for (int nt = 0; nt < 4; ++nt)
                orow[nt * 16 + lr] = acc[mt][nt][r] + bias[nt];
        }
    }
}

// ---------------------------------------------------------------------------
extern "C" void kernel_launch(void* const* d_in, const int* in_sizes, int n_in,
                              void* d_out, int out_size, void* d_ws, size_t ws_size,
                              hipStream_t stream) {
    const float* h    = (const float*)d_in[0];
    const int*   span = (const int*)  d_in[1];
    const float* Ws1  = (const float*)d_in[2];
    const float* bs1  = (const float*)d_in[3];
    const float* Ws2  = (const float*)d_in[4];
    const float* bs2  = (const float*)d_in[5];
    const float* We1  = (const float*)d_in[6];
    const float* be1  = (const float*)d_in[7];
    const float* We2  = (const float*)d_in[8];
    const float* be2  = (const float*)d_in[9];
    const float* Wo   = (const float*)d_in[10];
    const float* bo   = (const float*)d_in[11];
    const float* Wr1  = (const float*)d_in[12];
    const float* br1  = (const float*)d_in[13];
    const float* Wr2  = (const float*)d_in[14];
    const float* br2  = (const float*)d_in[15];
    float* out = (float*)d_out;

    dim3 blk(256);
    const size_t REQUIRED = (size_t)120 << 20;

    if (ws_size >= REQUIRED) {
        // ---------------- split-bf16 MFMA path ----------------
        char* W = (char*)d_ws;
        size_t off = 0;
        auto alloc = [&](size_t bytes) { char* q = W + off; off += bytes; return q; };

        u16* W1t_h = (u16*)alloc((size_t)2 * 2048 * 1024 * 2);
        u16* W1t_l = (u16*)alloc((size_t)2 * 2048 * 1024 * 2);
        u16* W2t_h = (u16*)alloc((size_t)2 * 1024 * 2048 * 2);
        u16* W2t_l = (u16*)alloc((size_t)2 * 1024 * 2048 * 2);
        u16* Wot_h = (u16*)alloc((size_t)2048 * 2048 * 2);
        u16* Wot_l = (u16*)alloc((size_t)2048 * 2048 * 2);
        u16* Wr1t_h = (u16*)alloc((size_t)2 * 2048 * 2048 * 2);
        u16* Wr1t_l = (u16*)alloc((size_t)2 * 2048 * 2048 * 2);
        u16* Wr2t_h = (u16*)alloc((size_t)1024 * 2048 * 2);
        u16* gs_h  = (u16*)alloc((size_t)2 * 512 * 1024 * 2);
        u16* gs_l  = (u16*)alloc((size_t)2 * 512 * 1024 * 2);
        u16* t1_h  = (u16*)alloc((size_t)2 * 512 * 2048 * 2);
        u16* t1_l  = (u16*)alloc((size_t)2 * 512 * 2048 * 2);
        u16* cat_h = (u16*)alloc((size_t)512 * 2048 * 2);
        u16* cat_l = (u16*)alloc((size_t)512 * 2048 * 2);
        u16* ent_h = (u16*)alloc((size_t)512 * 2048 * 2);
        u16* ent_l = (u16*)alloc((size_t)512 * 2048 * 2);
        float* hif = (float*)alloc((size_t)512 * 2048 * 4);
        float* hjf = (float*)alloc((size_t)512 * 2048 * 4);

        TransJobs J;
        J.src[0] = Ws1;  J.dh[0] = W1t_h;                J.dl[0] = W1t_l;                J.K[0] = 1024; J.N[0] = 2048; J.tiles[0] = 512;
        J.src[1] = We1;  J.dh[1] = W1t_h + 2048 * 1024;  J.dl[1] = W1t_l + 2048 * 1024;  J.K[1] = 1024; J.N[1] = 2048; J.tiles[1] = 512;
        J.src[2] = Ws2;  J.dh[2] = W2t_h;                J.dl[2] = W2t_l;                J.K[2] = 2048; J.N[2] = 1024; J.tiles[2] = 512;
        J.src[3] = We2;  J.dh[3] = W2t_h + 1024 * 2048;  J.dl[3] = W2t_l + 1024 * 2048;  J.K[3] = 2048; J.N[3] = 1024; J.tiles[3] = 512;
        J.src[4] = Wo;   J.dh[4] = Wot_h;                J.dl[4] = Wot_l;                J.K[4] = 2048; J.N[4] = 2048; J.tiles[4] = 1024;
        J.src[5] = Wr1;  J.dh[5] = Wr1t_h;               J.dl[5] = Wr1t_l;               J.K[5] = 2048; J.N[5] = 2048; J.tiles[5] = 1024;
        J.src[6] = Wr1 + (size_t)2048 * 2048;
                         J.dh[6] = Wr1t_h + (size_t)2048 * 2048; J.dl[6] = Wr1t_l + (size_t)2048 * 2048;
                                                                          J.K[6] = 2048; J.N[6] = 2048; J.tiles[6] = 1024;
        J.src[7] = Wr2;  J.dh[7] = Wr2t_h;               J.dl[7] = nullptr;              J.K[7] = 2048; J.N[7] = 1024; J.tiles[7] = 512;
        transpose_split<<<dim3(5632), blk, 0, stream>>>(J);

        gather_split<<<dim3(512, 2), blk, 0, stream>>>(h, span, gs_h, gs_l);

        GemmP p1 = {};
        p1.ah0 = gs_h; p1.ah1 = gs_h + 512 * 1024;
        p1.al0 = gs_l; p1.al1 = gs_l + 512 * 1024;
        p1.wh0 = W1t_h; p1.wh1 = W1t_h + 2048 * 1024;
        p1.wl0 = W1t_l; p1.wl1 = W1t_l + 2048 * 1024;
        p1.b0 = bs1; p1.b1 = be1;
        p1.oh0 = t1_h; p1.oh1 = t1_h + 512 * 2048;
        p1.ol0 = t1_l; p1.ol1 = t1_l + 512 * 2048;
        p1.K = 1024; p1.ldc = 2048; p1.coloff1 = 0; p1.NT = 32;
        gemm_split<true, true, true><<<dim3(512), blk, 0, stream>>>(p1);

        GemmP p2 = {};
        p2.ah0 = t1_h; p2.ah1 = t1_h + 512 * 2048;
        p2.al0 = t1_l; p2.al1 = t1_l + 512 * 2048;
        p2.wh0 = W2t_h; p2.wh1 = W2t_h + 1024 * 2048;
        p2.wl0 = W2t_l; p2.wl1 = W2t_l + 1024 * 2048;
        p2.b0 = bs2; p2.b1 = be2;
        p2.oh0 = cat_h; p2.oh1 = cat_h;
        p2.ol0 = cat_l; p2.ol1 = cat_l;
        p2.K = 2048; p2.ldc = 2048; p2.coloff1 = 1024; p2.NT = 16;
        gemm_split<true, true, true><<<dim3(256), blk, 0, stream>>>(p2);

        GemmP p3 = {};
        p3.ah0 = cat_h; p3.al0 = cat_l;
        p3.wh0 = Wot_h; p3.wl0 = Wot_l;
        p3.b0 = bo;
        p3.oh0 = ent_h; p3.ol0 = ent_l;
        p3.K = 2048; p3.ldc = 2048; p3.coloff1 = 0; p3.NT = 32;
        gemm_split<false, true, true><<<dim3(256), blk, 0, stream>>>(p3);

        GemmP p4 = {};
        p4.ah0 = ent_h; p4.ah1 = ent_h;
        p4.al0 = ent_l; p4.al1 = ent_l;
        p4.wh0 = Wr1t_h; p4.wh1 = Wr1t_h + (size_t)2048 * 2048;
        p4.wl0 = Wr1t_l; p4.wl1 = Wr1t_l + (size_t)2048 * 2048;
        p4.of0 = hif; p4.of1 = hjf;
        p4.K = 2048; p4.ldc = 2048; p4.coloff1 = 0; p4.NT = 32;
        gemm_split<false, false, false><<<dim3(512), blk, 0, stream>>>(p4);

        big_mfma<<<dim3(256, 4), dim3(512), 0, stream>>>(hif, hjf, br1, Wr2t_h, br2, out);
    } else {
        // ---------------- fp32 fallback (round-1 structure) ----------------
        u16* Wt = (u16*)d_ws;                               // 4 MB
        float* ws  = (float*)((char*)d_ws + (size_t)Dm * D2 * 2);
        float* gs  = ws;
        float* ge  = gs  + 512 * Dm;
        float* t1  = ge  + 512 * Dm;
        float* cat = t1  + 512 * D2;
        float* ent = cat + 512 * D2;
        float* hi  = ent + 512 * D2;
        float* hj  = hi  + 512 * D2;

        TransJobs J = {};
        J.src[0] = Wr2; J.dh[0] = Wt; J.dl[0] = nullptr;
        J.K[0] = 2048; J.N[0] = 1024; J.tiles[0] = 512;
        transpose_split<<<dim3(512), blk, 0, stream>>>(J);

        gather_rows<<<dim3(512, 2), blk, 0, stream>>>(h, span, gs, ge);
        gemm_f32<true,  true><<<dim3(8, 32), blk, 0, stream>>>(gs, Dm, Ws1, D2, bs1, t1, D2, Dm);
        gemm_f32<true,  true><<<dim3(8, 16), blk, 0, stream>>>(t1, D2, Ws2, Dm, bs2, cat, D2, D2);
        gemm_f32<true,  true><<<dim3(8, 32), blk, 0, stream>>>(ge, Dm, We1, D2, be1, t1, D2, Dm);
        gemm_f32<true,  true><<<dim3(8, 16), blk, 0, stream>>>(t1, D2, We2, Dm, be2, cat + Dm, D2, D2);
        gemm_f32<false, true><<<dim3(8, 32), blk, 0, stream>>>(cat, D2, Wo, D2, bo, ent, D2, D2);
        gemm_f32<false, false><<<dim3(8, 32), blk, 0, stream>>>(ent, D2, Wr1, D2, nullptr, hi, D2, D2);
        gemm_f32<false, false><<<dim3(8, 32), blk, 0, stream>>>(ent, D2, Wr1 + (size_t)D2 * D2, D2, nullptr, hj, D2, D2);
        big_mfma<<<dim3(256, 4), dim3(512), 0, stream>>>(hi, hj, br1, Wt, br2, out);
    }
}

// Round 7
// 473.113 us; speedup vs baseline: 1.3854x; 1.0084x over previous
//
#include <hip/hip_runtime.h>
#include <hip/hip_bf16.h>

// Problem constants: B=8, L=512, N=64, D=1024
constexpr int Lseq = 512;
constexpr int Nsp  = 64;
constexpr int Dm   = 1024;   // D
constexpr int D2   = 2048;   // 2D

typedef __attribute__((ext_vector_type(8))) short short8;
typedef __attribute__((ext_vector_type(4))) float floatx4;
typedef unsigned short u16;
typedef unsigned int   u32;

__device__ __forceinline__ u32 f2bf(float x) {
    u32 u = __float_as_uint(x);
    return (u + 0x7fffu + ((u >> 16) & 1u)) >> 16;   // RNE
}
__device__ __forceinline__ float bf2f(u32 hbits) {
    return __uint_as_float(hbits << 16);
}
__device__ __forceinline__ u32 pk2(float x0, float x1) {
    __hip_bfloat162 bb = __float22bfloat162_rn(make_float2(x0, x1));
    u32 r; __builtin_memcpy(&r, &bb, 4); return r;
}

// XOR swizzle for 64B-row LDS tiles (32 u16 per row): spread 16 same-chunk
// rows over all 8 bank quads.  u16-index form: idx ^= ((row>>1)&3)<<3.
// (big_mfma BK=32 tiles; measured 0 bank conflicts, R2.)
__device__ __forceinline__ int swz_idx(int row, int chunk8) {
    return (row * 32 + chunk8 * 8) ^ (((row >> 1) & 3) << 3);
}

// ---------------------------------------------------------------------------
// Gather h rows at span indices, emitting hi/lo bf16 split. grid (512,2).
// ---------------------------------------------------------------------------
__global__ __launch_bounds__(256)
void gather_split(const float* __restrict__ h, const int* __restrict__ span,
                  u16* __restrict__ g_hi, u16* __restrict__ g_lo)
{
    const int row = blockIdx.x, which = blockIdx.y;
    const int b = row >> 6;
    const int idx = span[row * 2 + which];
    const float4* src = (const float4*)(h + ((size_t)b * Lseq + idx) * Dm);
    float4 v = src[threadIdx.x];
    u32 h01 = pk2(v.x, v.y), h23 = pk2(v.z, v.w);
    u32 l01 = pk2(v.x - bf2f(h01 & 0xffffu), v.y - bf2f(h01 >> 16));
    u32 l23 = pk2(v.z - bf2f(h23 & 0xffffu), v.w - bf2f(h23 >> 16));
    size_t off = ((size_t)which * 512 + row) * Dm + (size_t)threadIdx.x * 4;
    *(uint2*)(g_hi + off) = make_uint2(h01, h23);
    *(uint2*)(g_lo + off) = make_uint2(l01, l23);
}

// Plain fp32 gather (fallback path)
__global__ __launch_bounds__(256)
void gather_rows(const float* __restrict__ h, const int* __restrict__ span,
                 float* __restrict__ gs, float* __restrict__ ge)
{
    const int row = blockIdx.x, which = blockIdx.y;
    const int b = row >> 6;
    const int idx = span[row * 2 + which];
    const float4* src = (const float4*)(h + ((size_t)b * Lseq + idx) * Dm);
    float4* dst = (float4*)((which ? ge : gs) + (size_t)row * Dm);
    dst[threadIdx.x] = src[threadIdx.x];
}

// ---------------------------------------------------------------------------
// Batched weight transpose+split: W[k][n] fp32 -> Wt_hi/lo[n][k] bf16.
// ---------------------------------------------------------------------------
struct TransJobs {
    const float* src[8];
    u16* dh[8];
    u16* dl[8];
    int K[8], N[8], tiles[8];
};

__global__ __launch_bounds__(256)
void transpose_split(TransJobs J)
{
    __shared__ float T[64][65];
    int b = blockIdx.x, j = 0;
    while (b >= J.tiles[j]) { b -= J.tiles[j]; ++j; }
    const float* src = J.src[j];
    const int K = J.K[j], N = J.N[j];
    const int tk = K >> 6;
    const int k0 = (b % tk) * 64, n0 = (b / tk) * 64;
    const int t = threadIdx.x, c = t & 63, r4 = t >> 6;
#pragma unroll
    for (int s = 0; s < 16; ++s) {
        int r = r4 * 16 + s;
        T[r][c] = src[(size_t)(k0 + r) * N + n0 + c];
    }
    __syncthreads();
    u16* dh = J.dh[j];
    u16* dl = J.dl[j];
#pragma unroll
    for (int s = 0; s < 16; ++s) {
        int n = r4 * 16 + s;
        float v = T[c][n];
        u32 hv = f2bf(v);
        dh[(size_t)(n0 + n) * K + k0 + c] = (u16)hv;
        if (dl) dl[(size_t)(n0 + n) * K + k0 + c] = (u16)f2bf(v - bf2f(hv));
    }
}

// ---------------------------------------------------------------------------
// Split-bf16 MFMA GEMM: C = act(A @ W + bias), A as hi/lo bf16 [M][K],
// W pre-transposed+split Wt_hi/lo[n][k]. Tile 64x64, K-step 64, 4 waves,
// XCD panel swizzle (R6), 2-deep pipeline with COUNTED vmcnt (v7 / T4).
//
// v7: the R5 dbuf still drained vmcnt(0) at every __syncthreads, exposing
// a full ~900cy LLC latency per K-step (measured ~4900 cyc/step). New
// schedule, per step t (prologue stages L0->buf0, L1->buf1):
//   vmcnt(8)  [own L(t) landed; in-order retire; last step vmcnt(0)]
//   s_barrier [everyone's L(t) landed]
//   ds_read + MFMA on buf[t&1]  (compiler lgkmcnt covers fragment reads)
//   sched_barrier + s_barrier    [no wave still reads buf[t&1]]
//   stage L(t+2) -> buf[t&1]
// Loads stay in flight ~2 steps; no vmcnt(0) in steady-state loop.
// ---------------------------------------------------------------------------
struct GemmP {
    const u16 *ah0, *ah1, *al0, *al1;
    const u16 *wh0, *wh1, *wl0, *wl1;
    const float *b0, *b1;
    float *of0, *of1;
    u16 *oh0, *oh1, *ol0, *ol1;
    int K, ldc, coloff1, NT;
};

template<bool RELU, bool BIAS, bool SPLIT_OUT>
__global__ __launch_bounds__(256)
void gemm_split(GemmP P)
{
    // [buf][64*64] per logical tile; 4 tiles, 2 buffers = 64 KB total.
    __shared__ __align__(16) u16 As_h[2 * 64 * 64];
    __shared__ __align__(16) u16 As_l[2 * 64 * 64];
    __shared__ __align__(16) u16 Bs_h[2 * 64 * 64];
    __shared__ __align__(16) u16 Bs_l[2 * 64 * 64];

    const int tid = threadIdx.x, w = tid >> 6, l = tid & 63;
    const int lr = l & 15, lq = l >> 4;

    // XCD-aware decode (R6): panel's 8 m-blocks share one XCD's L2.
    const int hb = blockIdx.x;
    const int xcd = hb & 7;
    const int j = hb >> 3;
    const int mb = j & 7;               // 8 m-tiles in all calls
    const int panel = (j >> 3) * 8 + xcd;
    const int nb = panel % P.NT;
    const int z  = panel / P.NT;

    const int m0 = mb * 64, n0 = nb * 64;
    const int K = P.K;

    const u16* ah = z ? P.ah1 : P.ah0;
    const u16* al = z ? P.al1 : P.al0;
    const u16* wh = z ? P.wh1 : P.wh0;
    const u16* wl = z ? P.wl1 : P.wl0;

    // Each wave stages one 64x64 bf16 tile (8 KB) via 8 global_load_lds.
    const u16* src; u16* ldst;
    if      (w == 0) { src = ah + (size_t)m0 * K; ldst = As_h; }
    else if (w == 1) { src = al + (size_t)m0 * K; ldst = As_l; }
    else if (w == 2) { src = wh + (size_t)n0 * K; ldst = Bs_h; }
    else             { src = wl + (size_t)n0 * K; ldst = Bs_l; }
    // pre-swizzled source chunk: linear LDS write lands swizzled layout
    const int schunk = (l & 7) ^ ((l >> 3) & 7);
    const u16* sl = src + (size_t)(l >> 3) * K + (size_t)schunk * 8;

    // fragment-read swizzle: row&7 == lr&7 for rows x*16+lr
    const int rswz = (lr & 7) << 3;

    floatx4 acc[4];
#pragma unroll
    for (int nt = 0; nt < 4; ++nt) acc[nt] = (floatx4){0.f, 0.f, 0.f, 0.f};

    auto stage = [&](int k0, int buf) {
        u16* ld = ldst + buf * 4096;
#pragma unroll
        for (int i = 0; i < 8; ++i)
            __builtin_amdgcn_global_load_lds(
                (const __attribute__((address_space(1))) u32*)(sl + (size_t)i * 8 * K + k0),
                (__attribute__((address_space(3))) u32*)(ld + i * 512), 16, 0, 0);
    };

    const int nsteps = K >> 6;   // >= 16 for all calls
    // ---- prologue: 2 tiles in flight ----
    stage(0, 0);
    stage(64, 1);

    for (int t = 0; t < nsteps; ++t) {
        // Own L(t) = oldest 8 outstanding (L(t+1)=8 newer). In-order retire
        // => vmcnt(8) proves L(t) landed. Last step: L(t+1) never issued,
        // so must drain fully.
        if (t + 1 < nsteps) asm volatile("s_waitcnt vmcnt(8)" ::: "memory");
        else                asm volatile("s_waitcnt vmcnt(0)" ::: "memory");
        __builtin_amdgcn_s_barrier();
        __builtin_amdgcn_sched_barrier(0);

        const int bo = (t & 1) * 4096;
#pragma unroll
        for (int kk = 0; kk < 2; ++kk) {
            const int ar = bo + ((((w * 16 + lr) * 64) + kk * 32 + lq * 8) ^ rswz);
            short8 fah = *(const short8*)&As_h[ar];
            short8 fal = *(const short8*)&As_l[ar];
#pragma unroll
            for (int nt = 0; nt < 4; ++nt) {
                const int brd = bo + ((((nt * 16 + lr) * 64) + kk * 32 + lq * 8) ^ rswz);
                short8 fbh = *(const short8*)&Bs_h[brd];
                short8 fbl = *(const short8*)&Bs_l[brd];
                acc[nt] = __builtin_amdgcn_mfma_f32_16x16x32_bf16(fah, fbh, acc[nt], 0, 0, 0);
                acc[nt] = __builtin_amdgcn_mfma_f32_16x16x32_bf16(fal, fbh, acc[nt], 0, 0, 0);
                acc[nt] = __builtin_amdgcn_mfma_f32_16x16x32_bf16(fah, fbl, acc[nt], 0, 0, 0);
            }
        }
        // All fragment ds_reads are consumed (compiler lgkmcnt before MFMAs)
        // by the time a wave reaches this barrier; after it, buf[t&1] is
        // safe to overwrite.
        __builtin_amdgcn_sched_barrier(0);
        __builtin_amdgcn_s_barrier();
        if (t + 2 < nsteps) stage((t + 2) * 64, t & 1);
    }

    const float* bias = z ? P.b1 : P.b0;
    const int colb = n0 + (z ? P.coloff1 : 0);
    float bv[4];
    if (BIAS) {
#pragma unroll
        for (int nt = 0; nt < 4; ++nt) bv[nt] = bias[n0 + nt * 16 + lr];
    }
#pragma unroll
    for (int nt = 0; nt < 4; ++nt) {
#pragma unroll
        for (int r = 0; r < 4; ++r) {
            float x = acc[nt][r];
            if (BIAS) x += bv[nt];
            if (RELU) x = fmaxf(x, 0.f);
            const int m = m0 + w * 16 + lq * 4 + r;
            const size_t oidx = (size_t)m * P.ldc + colb + nt * 16 + lr;
            if (SPLIT_OUT) {
                u16* oh = z ? P.oh1 : P.oh0;
                u16* ol = z ? P.ol1 : P.ol0;
                u32 hv = f2bf(x);
                oh[oidx] = (u16)hv;
                ol[oidx] = (u16)f2bf(x - bf2f(hv));
            } else {
                float* of = z ? P.of1 : P.of0;
                of[oidx] = x;
            }
        }
    }
}

// ---------------------------------------------------------------------------
// fp32 GEMM fallback (round-1) for small layers if ws is too small.
// ---------------------------------------------------------------------------
template<bool RELU, bool BIAS>
__global__ __launch_bounds__(256)
void gemm_f32(const float* __restrict__ A, int lda,
              const float* __restrict__ W, int ldw,
              const float* __restrict__ bias,
              float* __restrict__ C, int ldc, int K)
{
    __shared__ float As[16][64];
    __shared__ float Ws[16][64];
    const int tid = threadIdx.x;
    const int tx = tid & 15, ty = tid >> 4;
    const int m0 = blockIdx.x * 64, n0 = blockIdx.y * 64;
    const int la_c = tid & 15, la_r = tid >> 4;
    const int lw_n = tid & 63, lw_k = tid >> 6;
    float acc[4][4] = {};
    for (int k0 = 0; k0 < K; k0 += 16) {
#pragma unroll
        for (int s = 0; s < 4; ++s) {
            int m = la_r + 16 * s;
            As[la_c][m] = A[(size_t)(m0 + m) * lda + k0 + la_c];
        }
#pragma unroll
        for (int s = 0; s < 4; ++s) {
            int k = lw_k + 4 * s;
            Ws[k][lw_n] = W[(size_t)(k0 + k) * ldw + n0 + lw_n];
        }
        __syncthreads();
#pragma unroll
        for (int kk = 0; kk < 16; ++kk) {
            float a4[4], w4[4];
            *(float4*)a4 = *(const float4*)&As[kk][ty * 4];
            *(float4*)w4 = *(const float4*)&Ws[kk][tx * 4];
#pragma unroll
            for (int i = 0; i < 4; ++i)
#pragma unroll
                for (int j = 0; j < 4; ++j)
                    acc[i][j] = fmaf(a4[i], w4[j], acc[i][j]);
        }
        __syncthreads();
    }
#pragma unroll
    for (int i = 0; i < 4; ++i) {
        float4 v; float* vp = (float*)&v;
#pragma unroll
        for (int j = 0; j < 4; ++j) {
            float x = acc[i][j];
            if (BIAS) x += bias[n0 + tx * 4 + j];
            if (RELU) x = fmaxf(x, 0.f);
            vp[j] = x;
        }
        *(float4*)&C[(size_t)(m0 + ty * 4 + i) * ldc + n0 + tx * 4] = v;
    }
}

// ---------------------------------------------------------------------------
// Final GEMM via bf16 MFMA; hidden = relu(hi ⊕ hj + br1) built on the fly.
// 512 threads, 8 waves (wm 0..1 × wn 0..3), tile 128(M)x256(N), grid (256,4).
// R2-proven version: K-step 32, [row][32] tiles, XOR swizzle
// idx ^= ((row>>1)&3)<<3 on BOTH sides (A: per-lane ds_write + read;
// B: pre-swizzled global source + read).  B gload_lds before A-build VALU.
// NOTE: BK=64 here spills (reg budget 128 @ launch_bounds(512,4)) — R3
// measured 489 MiB scratch writes, 2x dur. Do not raise BK or add regs
// without watching WRITE_SIZE for the spill signature.
// ---------------------------------------------------------------------------
__global__ __launch_bounds__(512, 4)
void big_mfma(const float* __restrict__ hi, const float* __restrict__ hj,
              const float* __restrict__ br1, const u16* __restrict__ Wt,
              const float* __restrict__ br2, float* __restrict__ out)
{
    __shared__ float hiP[2][D2];                     // 16 KB
    __shared__ __align__(16) u16 Asb[128 * 32];      // swizzled [128][32], 8 KB
    __shared__ __align__(16) u16 Bsb[256 * 32];      // swizzled [256][32], 16 KB

    const int tid = threadIdx.x;
    const int p = blockIdx.x, n0 = blockIdx.y * 256;
    const int b = p >> 5, bi0 = p * 2;

    // A-build assignment: one (row, k-chunk) per thread.
    const int rowA = tid >> 2, kq = tid & 3;
    const int selA = rowA >> 6, jA = rowA & 63;
    const float* hjrow = hj + ((size_t)b * 64 + jA) * D2 + kq * 8;
    u16* astore = Asb + swz_idx(rowA, kq);
    const float* hip = hiP[selA] + kq * 8;

    // Prefetch hj chunk for k0=0 (in flight during hiP staging).
    float4 pf0 = *(const float4*)(hjrow);
    float4 pf1 = *(const float4*)(hjrow + 4);

    // hiP = hi(+pair) + br1  (1024 float4 over 512 threads)
    {
        const float4* h0 = (const float4*)(hi + (size_t)bi0 * D2);
        const float4* h1 = (const float4*)(hi + (size_t)(bi0 + 1) * D2);
        const float4* br = (const float4*)br1;
        float4* d0 = (float4*)hiP[0];
        float4* d1 = (float4*)hiP[1];
        const int v = tid;   // 512 threads, 512 float4 per row
        float4 bb = br[v];
        float4 a = h0[v];
        a.x += bb.x; a.y += bb.y; a.z += bb.z; a.w += bb.w;
        d0[v] = a;
        float4 c = h1[v];
        c.x += bb.x; c.y += bb.y; c.z += bb.z; c.w += bb.w;
        d1[v] = c;
    }

    const int w = tid >> 6, l = tid & 63;
    const int wm = w & 1, wn = w >> 1;
    const int lr = l & 15, lq = l >> 4;
    const int rswz = ((lr >> 1) & 3) << 3;

    // B source: pre-swizzled chunk so linear gload write == swizzled layout.
    const int schunk = (l & 3) ^ ((l >> 3) & 3);

    floatx4 acc[4][4];
#pragma unroll
    for (int mt = 0; mt < 4; ++mt)
#pragma unroll
        for (int nt = 0; nt < 4; ++nt)
            acc[mt][nt] = (floatx4){0.f, 0.f, 0.f, 0.f};

    for (int k0 = 0; k0 < D2; k0 += 32) {
        __syncthreads();

        // ---- B tile: async bf16 stage first (hides under A-build) ----
#pragma unroll
        for (int c = 0; c < 2; ++c) {
            const u16* g = Wt + (size_t)(n0 + w * 32 + c * 16 + (l >> 2)) * D2
                              + k0 + schunk * 8;
            u16* lp = Bsb + (w * 32 + c * 16) * 32;
            __builtin_amdgcn_global_load_lds(
                (const __attribute__((address_space(1))) u32*)g,
                (__attribute__((address_space(3))) u32*)lp, 16, 0, 0);
        }

        // ---- A tile: relu(hi' + hj) -> bf16, swizzled store ----
        {
            float4 h0 = *(const float4*)(hip + k0);
            float4 h1 = *(const float4*)(hip + k0 + 4);
            u32 u0 = pk2(fmaxf(pf0.x + h0.x, 0.f), fmaxf(pf0.y + h0.y, 0.f));
            u32 u1 = pk2(fmaxf(pf0.z + h0.z, 0.f), fmaxf(pf0.w + h0.w, 0.f));
            u32 u2 = pk2(fmaxf(pf1.x + h1.x, 0.f), fmaxf(pf1.y + h1.y, 0.f));
            u32 u3 = pk2(fmaxf(pf1.z + h1.z, 0.f), fmaxf(pf1.w + h1.w, 0.f));
            *(uint4*)astore = make_uint4(u0, u1, u2, u3);
        }

        __syncthreads();

        // ---- prefetch next-k hj (flies during MFMA cluster) ----
        if (k0 + 32 < D2) {
            pf0 = *(const float4*)(hjrow + k0 + 32);
            pf1 = *(const float4*)(hjrow + k0 + 36);
        }

        // ---- fragments + MFMA ----
        short8 af[4], bfr[4];
#pragma unroll
        for (int mt = 0; mt < 4; ++mt)
            af[mt] = *(const short8*)&Asb[(((wm * 64 + mt * 16 + lr) * 32) + lq * 8) ^ rswz];
#pragma unroll
        for (int nt = 0; nt < 4; ++nt)
            bfr[nt] = *(const short8*)&Bsb[(((wn * 64 + nt * 16 + lr) * 32) + lq * 8) ^ rswz];
        __builtin_amdgcn_s_setprio(1);
#pragma unroll
        for (int mt = 0; mt < 4; ++mt)
#pragma unroll
            for (int nt = 0; nt < 4; ++nt)
                acc[mt][nt] = __builtin_amdgcn_mfma_f32_16x16x32_bf16(
                    af[mt], bfr[nt], acc[mt][nt], 0, 0, 0);
        __builtin_amdgcn_s_setprio(0);
    }

    // ---- epilogue ----
    float bias[4];
#pragma unroll
    for (int nt = 0; nt < 4; ++nt)
        bias[nt] = br2[n0 + wn * 64 + nt * 16 + lr];

#pragma unroll
    for (int mt = 0; mt < 4; ++mt) {
        const int mbase = wm * 64 + mt * 16 + lq * 4;
#pragma unroll
        for (int r = 0; r < 4; ++r) {
            const int mm = mbase + r;
            const int sel = mm >> 6, j = mm & 63;
            float* orow = out + (((size_t)(bi0 + sel) * 64 + j) * Dm) + n0 + wn * 64;
#pragma unroll
            for (int nt = 0; nt < 4; ++nt)
                orow[nt * 16 + lr] = acc[mt][nt][r] + bias[nt];
        }
    }
}

// ---------------------------------------------------------------------------
extern "C" void kernel_launch(void* const* d_in, const int* in_sizes, int n_in,
                              void* d_out, int out_size, void* d_ws, size_t ws_size,
                              hipStream_t stream) {
    const float* h    = (const float*)d_in[0];
    const int*   span = (const int*)  d_in[1];
    const float* Ws1  = (const float*)d_in[2];
    const float* bs1  = (const float*)d_in[3];
    const float* Ws2  = (const float*)d_in[4];
    const float* bs2  = (const float*)d_in[5];
    const float* We1  = (const float*)d_in[6];
    const float* be1  = (const float*)d_in[7];
    const float* We2  = (const float*)d_in[8];
    const float* be2  = (const float*)d_in[9];
    const float* Wo   = (const float*)d_in[10];
    const float* bo   = (const float*)d_in[11];
    const float* Wr1  = (const float*)d_in[12];
    const float* br1  = (const float*)d_in[13];
    const float* Wr2  = (const float*)d_in[14];
    const float* br2  = (const float*)d_in[15];
    float* out = (float*)d_out;

    dim3 blk(256);
    const size_t REQUIRED = (size_t)120 << 20;

    if (ws_size >= REQUIRED) {
        // ---------------- split-bf16 MFMA path ----------------
        char* W = (char*)d_ws;
        size_t off = 0;
        auto alloc = [&](size_t bytes) { char* q = W + off; off += bytes; return q; };

        u16* W1t_h = (u16*)alloc((size_t)2 * 2048 * 1024 * 2);
        u16* W1t_l = (u16*)alloc((size_t)2 * 2048 * 1024 * 2);
        u16* W2t_h = (u16*)alloc((size_t)2 * 1024 * 2048 * 2);
        u16* W2t_l = (u16*)alloc((size_t)2 * 1024 * 2048 * 2);
        u16* Wot_h = (u16*)alloc((size_t)2048 * 2048 * 2);
        u16* Wot_l = (u16*)alloc((size_t)2048 * 2048 * 2);
        u16* Wr1t_h = (u16*)alloc((size_t)2 * 2048 * 2048 * 2);
        u16* Wr1t_l = (u16*)alloc((size_t)2 * 2048 * 2048 * 2);
        u16* Wr2t_h = (u16*)alloc((size_t)1024 * 2048 * 2);
        u16* gs_h  = (u16*)alloc((size_t)2 * 512 * 1024 * 2);
        u16* gs_l  = (u16*)alloc((size_t)2 * 512 * 1024 * 2);
        u16* t1_h  = (u16*)alloc((size_t)2 * 512 * 2048 * 2);
        u16* t1_l  = (u16*)alloc((size_t)2 * 512 * 2048 * 2);
        u16* cat_h = (u16*)alloc((size_t)512 * 2048 * 2);
        u16* cat_l = (u16*)alloc((size_t)512 * 2048 * 2);
        u16* ent_h = (u16*)alloc((size_t)512 * 2048 * 2);
        u16* ent_l = (u16*)alloc((size_t)512 * 2048 * 2);
        float* hif = (float*)alloc((size_t)512 * 2048 * 4);
        float* hjf = (float*)alloc((size_t)512 * 2048 * 4);

        TransJobs J;
        J.src[0] = Ws1;  J.dh[0] = W1t_h;                J.dl[0] = W1t_l;                J.K[0] = 1024; J.N[0] = 2048; J.tiles[0] = 512;
        J.src[1] = We1;  J.dh[1] = W1t_h + 2048 * 1024;  J.dl[1] = W1t_l + 2048 * 1024;  J.K[1] = 1024; J.N[1] = 2048; J.tiles[1] = 512;
        J.src[2] = Ws2;  J.dh[2] = W2t_h;                J.dl[2] = W2t_l;                J.K[2] = 2048; J.N[2] = 1024; J.tiles[2] = 512;
        J.src[3] = We2;  J.dh[3] = W2t_h + 1024 * 2048;  J.dl[3] = W2t_l + 1024 * 2048;  J.K[3] = 2048; J.N[3] = 1024; J.tiles[3] = 512;
        J.src[4] = Wo;   J.dh[4] = Wot_h;                J.dl[4] = Wot_l;                J.K[4] = 2048; J.N[4] = 2048; J.tiles[4] = 1024;
        J.src[5] = Wr1;  J.dh[5] = Wr1t_h;               J.dl[5] = Wr1t_l;               J.K[5] = 2048; J.N[5] = 2048; J.tiles[5] = 1024;
        J.src[6] = Wr1 + (size_t)2048 * 2048;
                         J.dh[6] = Wr1t_h + (size_t)2048 * 2048; J.dl[6] = Wr1t_l + (size_t)2048 * 2048;
                                                                          J.K[6] = 2048; J.N[6] = 2048; J.tiles[6] = 1024;
        J.src[7] = Wr2;  J.dh[7] = Wr2t_h;               J.dl[7] = nullptr;              J.K[7] = 2048; J.N[7] = 1024; J.tiles[7] = 512;
        transpose_split<<<dim3(5632), blk, 0, stream>>>(J);

        gather_split<<<dim3(512, 2), blk, 0, stream>>>(h, span, gs_h, gs_l);

        GemmP p1 = {};
        p1.ah0 = gs_h; p1.ah1 = gs_h + 512 * 1024;
        p1.al0 = gs_l; p1.al1 = gs_l + 512 * 1024;
        p1.wh0 = W1t_h; p1.wh1 = W1t_h + 2048 * 1024;
        p1.wl0 = W1t_l; p1.wl1 = W1t_l + 2048 * 1024;
        p1.b0 = bs1; p1.b1 = be1;
        p1.oh0 = t1_h; p1.oh1 = t1_h + 512 * 2048;
        p1.ol0 = t1_l; p1.ol1 = t1_l + 512 * 2048;
        p1.K = 1024; p1.ldc = 2048; p1.coloff1 = 0; p1.NT = 32;
        gemm_split<true, true, true><<<dim3(512), blk, 0, stream>>>(p1);

        GemmP p2 = {};
        p2.ah0 = t1_h; p2.ah1 = t1_h + 512 * 2048;
        p2.al0 = t1_l; p2.al1 = t1_l + 512 * 2048;
        p2.wh0 = W2t_h; p2.wh1 = W2t_h + 1024 * 2048;
        p2.wl0 = W2t_l; p2.wl1 = W2t_l + 1024 * 2048;
        p2.b0 = bs2; p2.b1 = be2;
        p2.oh0 = cat_h; p2.oh1 = cat_h;
        p2.ol0 = cat_l; p2.ol1 = cat_l;
        p2.K = 2048; p2.ldc = 2048; p2.coloff1 = 1024; p2.NT = 16;
        gemm_split<true, true, true><<<dim3(256), blk, 0, stream>>>(p2);

        GemmP p3 = {};
        p3.ah0 = cat_h; p3.al0 = cat_l;
        p3.wh0 = Wot_h; p3.wl0 = Wot_l;
        p3.b0 = bo;
        p3.oh0 = ent_h; p3.ol0 = ent_l;
        p3.K = 2048; p3.ldc = 2048; p3.coloff1 = 0; p3.NT = 32;
        gemm_split<false, true, true><<<dim3(256), blk, 0, stream>>>(p3);

        GemmP p4 = {};
        p4.ah0 = ent_h; p4.ah1 = ent_h;
        p4.al0 = ent_l; p4.al1 = ent_l;
        p4.wh0 = Wr1t_h; p4.wh1 = Wr1t_h + (size_t)2048 * 2048;
        p4.wl0 = Wr1t_l; p4.wl1 = Wr1t_l + (size_t)2048 * 2048;
        p4.of0 = hif; p4.of1 = hjf;
        p4.K = 2048; p4.ldc = 2048; p4.coloff1 = 0; p4.NT = 32;
        gemm_split<false, false, false><<<dim3(512), blk, 0, stream>>>(p4);

        big_mfma<<<dim3(256, 4), dim3(512), 0, stream>>>(hif, hjf, br1, Wr2t_h, br2, out);
    } else {
        // ---------------- fp32 fallback (round-1 structure) ----------------
        u16* Wt = (u16*)d_ws;                               // 4 MB
        float* ws  = (float*)((char*)d_ws + (size_t)Dm * D2 * 2);
        float* gs  = ws;
        float* ge  = gs  + 512 * Dm;
        float* t1  = ge  + 512 * Dm;
        float* cat = t1  + 512 * D2;
        float* ent = cat + 512 * D2;
        float* hi  = ent + 512 * D2;
        float* hj  = hi  + 512 * D2;

        TransJobs J = {};
        J.src[0] = Wr2; J.dh[0] = Wt; J.dl[0] = nullptr;
        J.K[0] = 2048; J.N[0] = 1024; J.tiles[0] = 512;
        transpose_split<<<dim3(512), blk, 0, stream>>>(J);

        gather_rows<<<dim3(512, 2), blk, 0, stream>>>(h, span, gs, ge);
        gemm_f32<true,  true><<<dim3(8, 32), blk, 0, stream>>>(gs, Dm, Ws1, D2, bs1, t1, D2, Dm);
        gemm_f32<true,  true><<<dim3(8, 16), blk, 0, stream>>>(t1, D2, Ws2, Dm, bs2, cat, D2, D2);
        gemm_f32<true,  true><<<dim3(8, 32), blk, 0, stream>>>(ge, Dm, We1, D2, be1, t1, D2, Dm);
        gemm_f32<true,  true><<<dim3(8, 16), blk, 0, stream>>>(t1, D2, We2, Dm, be2, cat + Dm, D2, D2);
        gemm_f32<false, true><<<dim3(8, 32), blk, 0, stream>>>(cat, D2, Wo, D2, bo, ent, D2, D2);
        gemm_f32<false, false><<<dim3(8, 32), blk, 0, stream>>>(ent, D2, Wr1, D2, nullptr, hi, D2, D2);
        gemm_f32<false, false><<<dim3(8, 32), blk, 0, stream>>>(ent, D2, Wr1 + (size_t)D2 * D2, D2, nullptr, hj, D2, D2);
        big_mfma<<<dim3(256, 4), dim3(512), 0, stream>>>(hi, hj, br1, Wt, br2, out);
    }
}